// Round 2
// baseline (808.463 us; speedup 1.0000x reference)
//
#include <hip/hip_runtime.h>
#include <hip/hip_bf16.h>
#include <hip/hip_fp16.h>

#define BATCH   8192
#define HID     1024
#define HEADS   8
#define BC      2048

typedef unsigned int  u32;
typedef unsigned short u16;
typedef __attribute__((ext_vector_type(8))) short bf16x8;
typedef __attribute__((ext_vector_type(4))) float f32x4;

// ---------------------------------------------------------------------------
// hi/lo split helpers (truncation both; x = hi + lo + O(2^-16 |x|))
// ---------------------------------------------------------------------------
__device__ __forceinline__ u32 pack_hi2(u32 u0, u32 u1) {
    return (u0 >> 16) | (u1 & 0xFFFF0000u);
}
__device__ __forceinline__ void split1(float x, u16& h, u16& l) {
    const u32 u = __float_as_uint(x);
    h = (u16)(u >> 16);
    const float r = x - __uint_as_float(u & 0xFFFF0000u);
    l = (u16)(__float_as_uint(r) >> 16);
}
__device__ __forceinline__ void splitA4(float4 v, uint2& hi, uint2& lo) {
    u32 u0 = __float_as_uint(v.x), u1 = __float_as_uint(v.y),
        u2 = __float_as_uint(v.z), u3 = __float_as_uint(v.w);
    float r0 = v.x - __uint_as_float(u0 & 0xFFFF0000u);
    float r1 = v.y - __uint_as_float(u1 & 0xFFFF0000u);
    float r2 = v.z - __uint_as_float(u2 & 0xFFFF0000u);
    float r3 = v.w - __uint_as_float(u3 & 0xFFFF0000u);
    hi.x = pack_hi2(u0, u1);
    hi.y = pack_hi2(u2, u3);
    lo.x = pack_hi2(__float_as_uint(r0), __float_as_uint(r1));
    lo.y = pack_hi2(__float_as_uint(r2), __float_as_uint(r3));
}

// async global->LDS, 16 B per lane; lds base must be wave-uniform
__device__ __forceinline__ void gld16(const u16* g, u16* l) {
    __builtin_amdgcn_global_load_lds(
        (const __attribute__((address_space(1))) u32*)g,
        (__attribute__((address_space(3))) u32*)l, 16, 0, 0);
}

// ---------------------------------------------------------------------------
// Combined weight conversion (ONE launch): 13 z-slices ->
//  z=0 eh, z=1 dh, z=2 w1, z=3..10 heads h, z=11 enc, z=12 dec
// W fp32 [K][1024] -> hi/lo planes, k-tiled transposed  Wt[kt][n][32].
// ---------------------------------------------------------------------------
struct WSplitArgs {
    const float* src[6];
    u16* hi[6];
    u16* lo[6];
};

__global__ __launch_bounds__(256) void split_weight_all(WSplitArgs args)
{
    const int z = blockIdx.z;
    int which, zz = 0;
    if (z < 3)       { which = z; }
    else if (z < 11) { which = 3; zz = z - 3; }
    else             { which = z - 7; }          // 4 = enc, 5 = dec
    const int KT = (which == 4) ? 17 : (which == 5 ? 3 : 32);
    const int kt = blockIdx.x;
    if (kt >= KT) return;
    const int K = KT * 32;
    const long long zoff = (long long)zz * K * 1024;
    const float* W  = args.src[which] + zoff;
    u16* hi = args.hi[which] + zoff;
    u16* lo = args.lo[which] + zoff;

    const int n0  = blockIdx.y * 128;
    const int tid = threadIdx.x;
    const int k   = tid >> 3;            // 0..31
    const int ng  = (tid & 7) * 16;      // 0,16,...,112
    const float* src = W + (long long)(kt * 32 + k) * 1024 + n0 + ng;
    u16* dh = hi + ((long long)kt * 1024 + n0) * 32 + k;
    u16* dl = lo + ((long long)kt * 1024 + n0) * 32 + k;
#pragma unroll
    for (int t = 0; t < 4; t++) {
        const float4 v = *(const float4*)(src + t * 4);
        u16 h0, l0, h1, l1, h2, l2, h3, l3;
        split1(v.x, h0, l0); split1(v.y, h1, l1);
        split1(v.z, h2, l2); split1(v.w, h3, l3);
        const int nb = (ng + t * 4) * 32;
        dh[nb]      = h0; dl[nb]      = l0;
        dh[nb + 32] = h1; dl[nb + 32] = l1;
        dh[nb + 64] = h2; dl[nb + 64] = l2;
        dh[nb + 96] = h3; dl[nb + 96] = l3;
    }
}

// ===========================================================================
// Hybrid deep-pipelined GEMM core (K = 1024 only; KT = 32 even):
//  - tile 256x128, 8 waves (512 thr), per-wave 64x64
//  - HI planes: global_load_lds into ring of 3 x 24 KiB (72 KiB total LDS)
//  - LO planes: direct global->VGPR, double-buffered (contiguous 1 KiB/instr)
//  - per K-tile: 8 ds_read_b128 + 3 gld16 + 8 lo-loads + 48 MFMA +
//    ONE vmcnt(11) + ONE raw s_barrier (no full drain anywhere in the loop)
//  - MFMA order: 16 hi*hi first, then hi*lo, lo*hi -> compiler's automatic
//    vmcnt wait for the lo regs lands mid-cluster (latency slack ~400cy)
//  - LDS traffic ~88 KB/K-tile/CU < MFMA 1546 cy  => MFMA-bound
// Swizzle identical to previous kernels (verified 0 bank conflicts).
// ===========================================================================
#define PIPE_GEOM \
    const int tid  = threadIdx.x; \
    const int lane = tid & 63; \
    const int wv   = tid >> 6; \
    const int wm   = wv >> 1, wn = wv & 1; \
    const int fr   = lane & 15; \
    const int fq   = lane >> 4; \
    const int m0   = blockIdx.y * 256; \
    const int n0   = blockIdx.x * 128; \
    const int lro2 = (lane >> 2) * 32 + (((lane & 3) ^ ((lane >> 3) & 3)) * 8); \
    const int fqx2 = (fq ^ ((fr >> 1) & 3)) * 8; \
    const int wr   = wv * 16;

// one ring buffer = 12288 shorts: A-hi [0,8192), B-hi [8192,12288)
#define PSTAGE(bi_, t_) { \
    u16* db_ = smem + (bi_) * 12288; \
    const long long ao_ = abase + (long long)(t_) * astep; \
    const long long bo_ = bbase + (long long)(t_) * 32768; \
    gld16(Ahp + ao_ + (long long)wr * 32 + lro2, db_ + wr * 32); \
    gld16(Ahp + ao_ + (long long)(128 + wr) * 32 + lro2, db_ + (128 + wr) * 32); \
    gld16(Bhp + bo_ + (long long)wr * 32 + lro2, db_ + 8192 + wr * 32); }

#define PLO(la_, lb_, t_) { \
    const long long ao_ = abase + (long long)(t_) * astep; \
    const long long bo_ = bbase + (long long)(t_) * 32768; \
    _Pragma("unroll") \
    for (int i_ = 0; i_ < 4; i_++) { \
        la_[i_] = *(const bf16x8*)(Alp + ao_ + (long long)(wm * 64 + i_ * 16 + fr) * 32 + fq * 8); \
        lb_[i_] = *(const bf16x8*)(Blp + bo_ + (long long)(wn * 64 + i_ * 16 + fr) * 32 + fq * 8); } }

#define PFRAGS(bi_) \
    const u16* bufp_ = smem + (bi_) * 12288; \
    bf16x8 ah[4], bh[4]; \
    _Pragma("unroll") \
    for (int i_ = 0; i_ < 4; i_++) \
        ah[i_] = *(const bf16x8*)(bufp_ + (wm * 64 + i_ * 16 + fr) * 32 + fqx2); \
    _Pragma("unroll") \
    for (int j_ = 0; j_ < 4; j_++) \
        bh[j_] = *(const bf16x8*)(bufp_ + 8192 + (wn * 64 + j_ * 16 + fr) * 32 + fqx2);

#define PMFMA(la_, lb_) \
    __builtin_amdgcn_sched_barrier(0); \
    __builtin_amdgcn_s_setprio(1); \
    _Pragma("unroll") \
    for (int i_ = 0; i_ < 4; i_++) \
        _Pragma("unroll") \
        for (int j_ = 0; j_ < 4; j_++) \
            acc[i_][j_] = __builtin_amdgcn_mfma_f32_16x16x32_bf16(ah[i_], bh[j_], acc[i_][j_], 0, 0, 0); \
    _Pragma("unroll") \
    for (int i_ = 0; i_ < 4; i_++) \
        _Pragma("unroll") \
        for (int j_ = 0; j_ < 4; j_++) \
            acc[i_][j_] = __builtin_amdgcn_mfma_f32_16x16x32_bf16(ah[i_], lb_[j_], acc[i_][j_], 0, 0, 0); \
    _Pragma("unroll") \
    for (int i_ = 0; i_ < 4; i_++) \
        _Pragma("unroll") \
        for (int j_ = 0; j_ < 4; j_++) \
            acc[i_][j_] = __builtin_amdgcn_mfma_f32_16x16x32_bf16(la_[i_], bh[j_], acc[i_][j_], 0, 0, 0); \
    __builtin_amdgcn_s_setprio(0);

#define PBAR(W_) \
    asm volatile("s_waitcnt vmcnt(" #W_ ")" ::: "memory"); \
    __builtin_amdgcn_s_barrier(); \
    __builtin_amdgcn_sched_barrier(0);

#define PIPE_LOOP \
    const int KT = K >> 5; \
    const long long astep = (long long)MA * 32; \
    const long long abase = ((long long)moff + m0) * 32; \
    const long long bbase = (long long)n0 * 32; \
    bf16x8 loAa[4], loAb[4], loBa[4], loBb[4]; \
    PSTAGE(0, 0); \
    PSTAGE(1, 1); \
    PLO(loAa, loAb, 0); \
    PBAR(11) \
    int be = 0, bo = 1, bs = 2; \
    for (int t = 0; t + 2 < KT; t += 2) { \
        { PFRAGS(be) PSTAGE(bs, t + 2); PLO(loBa, loBb, t + 1); \
          PMFMA(loAa, loAb) PBAR(11) } \
        { PFRAGS(bo) PSTAGE(be, t + 3); PLO(loAa, loAb, t + 2); \
          PMFMA(loBa, loBb) PBAR(11) } \
        const int nb_ = bs; bs = bo; bo = be; be = nb_; \
    } \
    { PFRAGS(be) PLO(loBa, loBb, KT - 1); PMFMA(loAa, loAb) PBAR(8) } \
    { PFRAGS(bo) PMFMA(loBa, loBb) }

// ===========================================================================
// GEMM (fast path, K=1024).  OUTP=1: write hi/lo planes.
// OUTP=0: fp32 row-major [*, 1024].
// ===========================================================================
template <int RELU, int OUTP>
__global__ __launch_bounds__(512, 2) void gemm_fast(
    const u16* __restrict__ Ahp, const u16* __restrict__ Alp, int MA, int moff,
    const u16* __restrict__ Bhp, const u16* __restrict__ Blp,
    const float* __restrict__ bias,
    float* __restrict__ Cf,
    u16* __restrict__ Chp, u16* __restrict__ Clp, int MC,
    int K)
{
    __shared__ alignas(16) u16 smem[3 * 12288];
    PIPE_GEOM

    f32x4 acc[4][4];
#pragma unroll
    for (int i = 0; i < 4; i++)
#pragma unroll
        for (int j = 0; j < 4; j++) acc[i][j] = 0;

    PIPE_LOOP

#pragma unroll
    for (int j = 0; j < 4; j++) {
        const int n = n0 + wn * 64 + j * 16 + fr;
        const float bb = bias[n];
#pragma unroll
        for (int i = 0; i < 4; i++) {
#pragma unroll
            for (int r = 0; r < 4; r++) {
                const int m = m0 + wm * 64 + i * 16 + fq * 4 + r;
                float v = acc[i][j][r] + bb;
                if (RELU) v = fmaxf(v, 0.0f);
                if (OUTP) {
                    u16 h, l;
                    split1(v, h, l);
                    const long long d = ((long long)(n >> 5) * MC + moff + m) * 32 + (n & 31);
                    Chp[d] = h;
                    Clp[d] = l;
                } else {
                    Cf[(long long)m * 1024 + n] = v;
                }
            }
        }
    }
}

// ===========================================================================
// Heads: per-head pipelined hybrid GEMM; epilogue writes relu(head) fp16 +
// partial score dots vs decH.  Grid (8, BC/256, 8), 512 threads.
// ===========================================================================
__global__ __launch_bounds__(512, 2) void heads_kernel(
    const u16* __restrict__ Ahp, const u16* __restrict__ Alp, int MA, int moff,
    const u16* __restrict__ Whp, const u16* __restrict__ Wlp,
    const float* __restrict__ b_heads,
    const float* __restrict__ decH,      // chunk-local [BC][1024]
    __half* __restrict__ headsb,         // [BC][8][1024]
    float* __restrict__ scoresp)         // [64][BC]
{
    __shared__ alignas(16) u16 smem[3 * 12288];
    __shared__ float scred[2][256];
    PIPE_GEOM
    const int h = blockIdx.z;
    const u16* Bhp = Whp + (long long)h * 1048576;
    const u16* Blp = Wlp + (long long)h * 1048576;
    const float* bias = b_heads + h * 1024;
    const int K = 1024;

    f32x4 acc[4][4];
#pragma unroll
    for (int i = 0; i < 4; i++)
#pragma unroll
        for (int j = 0; j < 4; j++) acc[i][j] = 0;

    PIPE_LOOP

    // epilogue: relu -> fp16 headsb, partial score vs decH
    float part[4][4];
#pragma unroll
    for (int i = 0; i < 4; i++)
#pragma unroll
        for (int r = 0; r < 4; r++) part[i][r] = 0.0f;

#pragma unroll
    for (int j = 0; j < 4; j++) {
        const int n = n0 + wn * 64 + j * 16 + fr;
        const float bb = bias[n];
#pragma unroll
        for (int i = 0; i < 4; i++) {
#pragma unroll
            for (int r = 0; r < 4; r++) {
                const int b_loc = m0 + wm * 64 + i * 16 + fq * 4 + r;
                const float v = fmaxf(acc[i][j][r] + bb, 0.0f);
                headsb[((long long)b_loc * HEADS + h) * 1024 + n] = __float2half(v);
                part[i][r] = fmaf(v, decH[(long long)b_loc * 1024 + n], part[i][r]);
            }
        }
    }
#pragma unroll
    for (int off = 1; off < 16; off <<= 1)
#pragma unroll
        for (int i = 0; i < 4; i++)
#pragma unroll
            for (int r = 0; r < 4; r++)
                part[i][r] += __shfl_xor(part[i][r], off, 64);

    if (fr == 0) {
#pragma unroll
        for (int i = 0; i < 4; i++)
#pragma unroll
            for (int r = 0; r < 4; r++)
                scred[wn][wm * 64 + i * 16 + fq * 4 + r] = part[i][r];
    }
    __syncthreads();
    if (tid < 256) {
        const float sv = scred[0][tid] + scred[1][tid];
        scoresp[(long long)(h * 8 + blockIdx.x) * BC + m0 + tid] = sv;
    }
}

// ===========================================================================
// GEMM (convert path, enc/dec): A fp32 (2-region concat), split in-kernel
// via LDS; B async from planes (r5 structure).  Output: hi/lo planes.
// ===========================================================================
template <int RELU>
__global__ __launch_bounds__(256) void gemm_cvt(
    const float* __restrict__ src1, int lda1, int kofs1,
    const float* __restrict__ src2, int lda2, int ksplit,
    const u16* __restrict__ Bhp, const u16* __restrict__ Blp,
    const float* __restrict__ bias,
    u16* __restrict__ Chp, u16* __restrict__ Clp, int MC,
    int K)
{
    __shared__ alignas(16) u16 Ah[4096], Al[4096], Bh[4096], Bl[4096];
    const int tid  = threadIdx.x;
    const int lane = tid & 63;
    const int wv   = tid >> 6;
    const int wm   = wv >> 1, wn = wv & 1;
    const int fr   = lane & 15;
    const int fq   = lane >> 4;
    const int m0   = blockIdx.y * 128;
    const int n0   = blockIdx.x * 128;
    const int fqx  = (fq ^ (fr & 3)) * 8;
    const int lro  = (lane >> 2) * 32 + (((lane & 3) ^ ((lane >> 2) & 3)) * 8);
    const int br0  = wv * 16;
    const int br1  = 64 + wv * 16;
    const int ar   = tid >> 3;           // 0..31
    const int akq  = tid & 7;            // float4 group 0..7
    const int awoff = (((akq >> 1) ^ (ar & 3)) * 8) + (akq & 1) * 4;

    f32x4 acc[4][4];
#pragma unroll
    for (int i = 0; i < 4; i++)
#pragma unroll
        for (int j = 0; j < 4; j++) acc[i][j] = 0;

    const int KT = K >> 5;
    for (int kt = 0; kt < KT; kt++) {
        const int k0 = kt * 32;
        const float* srcp; int ldk, kc;
        if (k0 < ksplit) { srcp = src1; ldk = lda1; kc = k0 + kofs1; }
        else             { srcp = src2; ldk = lda2; kc = k0 - ksplit; }

        const u16* Bg  = Bhp + ((long long)kt * 1024 + n0) * 32;
        const u16* Bg2 = Blp + ((long long)kt * 1024 + n0) * 32;
        gld16(Bg  + br0 * 32 + lro, &Bh[br0 * 32]);
        gld16(Bg  + br1 * 32 + lro, &Bh[br1 * 32]);
        gld16(Bg2 + br0 * 32 + lro, &Bl[br0 * 32]);
        gld16(Bg2 + br1 * 32 + lro, &Bl[br1 * 32]);

#pragma unroll
        for (int it = 0; it < 4; it++) {
            const int row = ar + it * 32;
            const float4 v = *(const float4*)(srcp + (long long)(m0 + row) * ldk + kc + akq * 4);
            uint2 hi, lo;
            splitA4(v, hi, lo);
            *(uint2*)&Ah[row * 32 + awoff] = hi;
            *(uint2*)&Al[row * 32 + awoff] = lo;
        }
        __syncthreads();

        bf16x8 ah[4], al[4], bh[4], bl[4];
#pragma unroll
        for (int i = 0; i < 4; i++) {
            const int off = (wm * 64 + i * 16 + fr) * 32 + fqx;
            ah[i] = *(const bf16x8*)&Ah[off];
            al[i] = *(const bf16x8*)&Al[off];
        }
#pragma unroll
        for (int j = 0; j < 4; j++) {
            const int off = (wn * 64 + j * 16 + fr) * 32 + fqx;
            bh[j] = *(const bf16x8*)&Bh[off];
            bl[j] = *(const bf16x8*)&Bl[off];
        }
#pragma unroll
        for (int i = 0; i < 4; i++)
#pragma unroll
            for (int j = 0; j < 4; j++) {
                acc[i][j] = __builtin_amdgcn_mfma_f32_16x16x32_bf16(ah[i], bh[j], acc[i][j], 0, 0, 0);
                acc[i][j] = __builtin_amdgcn_mfma_f32_16x16x32_bf16(ah[i], bl[j], acc[i][j], 0, 0, 0);
                acc[i][j] = __builtin_amdgcn_mfma_f32_16x16x32_bf16(al[i], bh[j], acc[i][j], 0, 0, 0);
            }
        __syncthreads();
    }

#pragma unroll
    for (int j = 0; j < 4; j++) {
        const int n = n0 + wn * 64 + j * 16 + fr;
        const float bb = bias[n];
#pragma unroll
        for (int i = 0; i < 4; i++) {
#pragma unroll
            for (int r = 0; r < 4; r++) {
                const int m = m0 + wm * 64 + i * 16 + fq * 4 + r;
                float v = acc[i][j][r] + bb;
                if (RELU) v = fmaxf(v, 0.0f);
                u16 h, l;
                split1(v, h, l);
                const long long d = ((long long)(n >> 5) * MC + m) * 32 + (n & 31);
                Chp[d] = h;
                Clp[d] = l;
            }
        }
    }
}

// ---------------------------------------------------------------------------
// context (+fused softmax): per row b, softmax over heads from scoresp,
// then ctx[b][d] = sum_h attn[h]*heads[b][h][d]; writes hi/lo planes.
// ---------------------------------------------------------------------------
__global__ __launch_bounds__(256) void context_kernel(
    const __half* __restrict__ headsb, const float* __restrict__ scoresp,
    u16* __restrict__ ctx_hi, u16* __restrict__ ctx_lo, int MC, int row0)
{
    __shared__ float sc_s[64];
    __shared__ float attn_s[HEADS];
    const int b = blockIdx.x;
    const int tid = threadIdx.x;
    if (tid < 64) sc_s[tid] = scoresp[(long long)tid * BC + b];
    __syncthreads();
    if (tid == 0) {
        float sc[HEADS];
#pragma unroll
        for (int h = 0; h < HEADS; h++) {
            float s = 0.0f;
#pragma unroll
            for (int nt = 0; nt < 8; nt++) s += sc_s[h * 8 + nt];
            sc[h] = s;
        }
        float mx = sc[0];
#pragma unroll
        for (int h = 1; h < HEADS; h++) mx = fmaxf(mx, sc[h]);
        float e[HEADS], sum = 0.0f;
#pragma unroll
        for (int h = 0; h < HEADS; h++) { e[h] = __expf(sc[h] - mx); sum += e[h]; }
        const float inv = 1.0f / sum;
#pragma unroll
        for (int h = 0; h < HEADS; h++) attn_s[h] = e[h] * inv;
    }
    __syncthreads();

    const int d = tid * 4;
    float w[HEADS];
#pragma unroll
    for (int h = 0; h < HEADS; h++) w[h] = attn_s[h];
    float4 acc = make_float4(0.f, 0.f, 0.f, 0.f);
#pragma unroll
    for (int h = 0; h < HEADS; h++) {
        const __half2* hp = (const __half2*)(headsb + ((long long)b * HEADS + h) * 1024 + d);
        const float2 f0 = __half22float2(hp[0]);
        const float2 f1 = __half22float2(hp[1]);
        acc.x = fmaf(w[h], f0.x, acc.x);
        acc.y = fmaf(w[h], f0.y, acc.y);
        acc.z = fmaf(w[h], f1.x, acc.z);
        acc.w = fmaf(w[h], f1.y, acc.w);
    }
    uint2 hi, lo;
    splitA4(acc, hi, lo);
    const long long off = ((long long)(d >> 5) * MC + row0 + b) * 32 + (d & 31);
    *(uint2*)(ctx_hi + off) = hi;
    *(uint2*)(ctx_lo + off) = lo;
}

// ---------------------------------------------------------------------------
// fc2: q[b] = sum_d x[b,d]*W2[d] + b2[0]
// ---------------------------------------------------------------------------
__global__ __launch_bounds__(256) void fc2_kernel(
    const float* __restrict__ x, const float* __restrict__ W2,
    const float* __restrict__ b2, float* __restrict__ q)
{
    const int b   = blockIdx.x;
    const int tid = threadIdx.x;
    __shared__ float red[4];

    const float4 xv = *(const float4*)(x + (long long)b * 1024 + tid * 4);
    const float4 wv = *(const float4*)(W2 + tid * 4);
    float p = xv.x * wv.x + xv.y * wv.y + xv.z * wv.z + xv.w * wv.w;
#pragma unroll
    for (int off = 32; off > 0; off >>= 1) p += __shfl_down(p, off, 64);
    if ((tid & 63) == 0) red[tid >> 6] = p;
    __syncthreads();
    if (tid == 0) q[b] = red[0] + red[1] + red[2] + red[3] + b2[0];
}

// ---------------------------------------------------------------------------
extern "C" void kernel_launch(void* const* d_in, const int* in_sizes, int n_in,
                              void* d_out, int out_size, void* d_ws, size_t ws_size,
                              hipStream_t stream)
{
    const float* s        = (const float*)d_in[0];
    const float* a        = (const float*)d_in[1];
    const float* W_enc_in = (const float*)d_in[2];
    const float* b_enc_in = (const float*)d_in[3];
    const float* W_dec_in = (const float*)d_in[4];
    const float* b_dec_in = (const float*)d_in[5];
    const float* W_eh     = (const float*)d_in[6];
    const float* b_eh     = (const float*)d_in[7];
    const float* W_heads  = (const float*)d_in[8];
    const float* b_heads  = (const float*)d_in[9];
    const float* W_dh     = (const float*)d_in[10];
    const float* b_dh     = (const float*)d_in[11];
    const float* W1       = (const float*)d_in[12];
    const float* b1       = (const float*)d_in[13];
    const float* W2       = (const float*)d_in[14];
    const float* b2       = (const float*)d_in[15];
    float* q_out = (float*)d_out;

    // ---- weight plane layout (shorts) -------------------------------------
    u16* P = (u16*)d_ws;
    u16* enc_hi = P; P += 557056;      // 544*1024
    u16* enc_lo = P; P += 557056;
    u16* dec_hi = P; P += 98304;       // 96*1024
    u16* dec_lo = P; P += 98304;
    u16* eh_hi  = P; P += 1048576;
    u16* eh_lo  = P; P += 1048576;
    u16* dh_hi  = P; P += 1048576;
    u16* dh_lo  = P; P += 1048576;
    u16* w1_hi  = P; P += 1048576;
    u16* w1_lo  = P; P += 1048576;
    u16* wh_hi  = P; P += 8388608;     // 8*1024*1024
    u16* wh_lo  = P; P += 8388608;
    char* act = (char*)P;              // 48,758,784 bytes consumed

    const dim3 blk(256);
    const dim3 blk512(512);

    // ---- weight conversions: ONE launch -----------------------------------
    WSplitArgs wa;
    wa.src[0] = W_eh;    wa.hi[0] = eh_hi;  wa.lo[0] = eh_lo;
    wa.src[1] = W_dh;    wa.hi[1] = dh_hi;  wa.lo[1] = dh_lo;
    wa.src[2] = W1;      wa.hi[2] = w1_hi;  wa.lo[2] = w1_lo;
    wa.src[3] = W_heads; wa.hi[3] = wh_hi;  wa.lo[3] = wh_lo;
    wa.src[4] = W_enc_in; wa.hi[4] = enc_hi; wa.lo[4] = enc_lo;
    wa.src[5] = W_dec_in; wa.hi[5] = dec_hi; wa.lo[5] = dec_lo;
    split_weight_all<<<dim3(32, 8, 13), blk, 0, stream>>>(wa);

    const bool high = (ws_size >= 150011904ULL);

    if (high) {
        u16*    bufA_hi = (u16*)act;
        u16*    bufA_lo = bufA_hi + 8388608;
        __half* headsb  = (__half*)act;
        u16*    encH_hi = (u16*)(act + 33554432);
        u16*    encH_lo = encH_hi + 8388608;
        float*  decH    = (float*)(act + 2LL * 33554432);
        float*  scoresp = (float*)(act + 3LL * 33554432);

        const dim3 ggc(8, 64, 1);      // cvt kernels: 128-row tiles
        const dim3 ggf(8, 32, 1);      // pipelined kernels: 256-row tiles
        gemm_cvt<0><<<ggc, blk, 0, stream>>>(s, 512, 0, a, 128, 512,
            enc_hi, enc_lo, b_enc_in, bufA_hi, bufA_lo, 8192, 544);
        gemm_fast<1, 1><<<ggf, blk512, 0, stream>>>(bufA_hi, bufA_lo, 8192, 0,
            eh_hi, eh_lo, b_eh, nullptr, encH_hi, encH_lo, 8192, 1024);
        gemm_cvt<0><<<ggc, blk, 0, stream>>>(a, 128, 32, a, 128, 1 << 28,
            dec_hi, dec_lo, b_dec_in, bufA_hi, bufA_lo, 8192, 96);
        gemm_fast<1, 0><<<ggf, blk512, 0, stream>>>(bufA_hi, bufA_lo, 8192, 0,
            dh_hi, dh_lo, b_dh, decH, nullptr, nullptr, 0, 1024);

        for (int c = 0; c < BATCH / BC; c++) {
            heads_kernel<<<dim3(8, BC / 256, 8), blk512, 0, stream>>>(
                encH_hi, encH_lo, 8192, c * BC, wh_hi, wh_lo, b_heads,
                decH + (long long)c * BC * 1024, headsb, scoresp);
            context_kernel<<<dim3(BC), blk, 0, stream>>>(
                headsb, scoresp, encH_hi, encH_lo, 8192, c * BC);
        }
        gemm_fast<1, 0><<<ggf, blk512, 0, stream>>>(encH_hi, encH_lo, 8192, 0,
            w1_hi, w1_lo, b1, decH, nullptr, nullptr, 0, 1024);
        fc2_kernel<<<dim3(BATCH), blk, 0, stream>>>(decH, W2, b2, q_out);
    } else {
        __half* headsb  = (__half*)act;
        u16*    bufA_hi = (u16*)act;
        u16*    bufA_lo = bufA_hi + 2097152;
        u16*    encH_hi = (u16*)(act + 33554432);
        u16*    encH_lo = encH_hi + 2097152;
        float*  decH    = (float*)(act + 33554432 + 8388608);
        float*  scoresp = (float*)(act + 33554432 + 2LL * 8388608);

        const dim3 ggc(8, BC / 128, 1);
        const dim3 ggf(8, BC / 256, 1);
        for (int c = 0; c < BATCH / BC; c++) {
            const float* sC = s + (long long)c * BC * 512;
            const float* aC = a + (long long)c * BC * 128;
            gemm_cvt<0><<<ggc, blk, 0, stream>>>(sC, 512, 0, aC, 128, 512,
                enc_hi, enc_lo, b_enc_in, bufA_hi, bufA_lo, BC, 544);
            gemm_fast<1, 1><<<ggf, blk512, 0, stream>>>(bufA_hi, bufA_lo, BC, 0,
                eh_hi, eh_lo, b_eh, nullptr, encH_hi, encH_lo, BC, 1024);
            gemm_cvt<0><<<ggc, blk, 0, stream>>>(aC, 128, 32, aC, 128, 1 << 28,
                dec_hi, dec_lo, b_dec_in, bufA_hi, bufA_lo, BC, 96);
            gemm_fast<1, 0><<<ggf, blk512, 0, stream>>>(bufA_hi, bufA_lo, BC, 0,
                dh_hi, dh_lo, b_dh, decH, nullptr, nullptr, 0, 1024);
            heads_kernel<<<dim3(8, BC / 256, 8), blk512, 0, stream>>>(
                encH_hi, encH_lo, BC, 0, wh_hi, wh_lo, b_heads,
                decH, headsb, scoresp);
            context_kernel<<<dim3(BC), blk, 0, stream>>>(
                headsb, scoresp, encH_hi, encH_lo, BC, 0);
            gemm_fast<1, 0><<<ggf, blk512, 0, stream>>>(encH_hi, encH_lo, BC, 0,
                w1_hi, w1_lo, b1, decH, nullptr, nullptr, 0, 1024);
            fc2_kernel<<<dim3(BC), blk, 0, stream>>>(decH, W2, b2, q_out + (long long)c * BC);
        }
    }
}

// Round 3
// 751.347 us; speedup vs baseline: 1.0760x; 1.0760x over previous
//
#include <hip/hip_runtime.h>
#include <hip/hip_bf16.h>
#include <hip/hip_fp16.h>

#define BATCH   8192
#define HID     1024
#define HEADS   8
#define BC      2048

typedef unsigned int  u32;
typedef unsigned short u16;
typedef __attribute__((ext_vector_type(8))) short bf16x8;
typedef __attribute__((ext_vector_type(4))) float f32x4;

// ---------------------------------------------------------------------------
// hi/lo split helpers (truncation both; x = hi + lo + O(2^-16 |x|))
// ---------------------------------------------------------------------------
__device__ __forceinline__ u32 pack_hi2(u32 u0, u32 u1) {
    return (u0 >> 16) | (u1 & 0xFFFF0000u);
}
__device__ __forceinline__ void split1(float x, u16& h, u16& l) {
    const u32 u = __float_as_uint(x);
    h = (u16)(u >> 16);
    const float r = x - __uint_as_float(u & 0xFFFF0000u);
    l = (u16)(__float_as_uint(r) >> 16);
}
__device__ __forceinline__ void splitA4(float4 v, uint2& hi, uint2& lo) {
    u32 u0 = __float_as_uint(v.x), u1 = __float_as_uint(v.y),
        u2 = __float_as_uint(v.z), u3 = __float_as_uint(v.w);
    float r0 = v.x - __uint_as_float(u0 & 0xFFFF0000u);
    float r1 = v.y - __uint_as_float(u1 & 0xFFFF0000u);
    float r2 = v.z - __uint_as_float(u2 & 0xFFFF0000u);
    float r3 = v.w - __uint_as_float(u3 & 0xFFFF0000u);
    hi.x = pack_hi2(u0, u1);
    hi.y = pack_hi2(u2, u3);
    lo.x = pack_hi2(__float_as_uint(r0), __float_as_uint(r1));
    lo.y = pack_hi2(__float_as_uint(r2), __float_as_uint(r3));
}

// async global->LDS, 16 B per lane; lds base must be wave-uniform
__device__ __forceinline__ void gld16(const u16* g, u16* l) {
    __builtin_amdgcn_global_load_lds(
        (const __attribute__((address_space(1))) u32*)g,
        (__attribute__((address_space(3))) u32*)l, 16, 0, 0);
}

// ---------------------------------------------------------------------------
// Combined weight conversion (ONE launch): 13 z-slices ->
//  z=0 eh, z=1 dh, z=2 w1, z=3..10 heads h, z=11 enc, z=12 dec
// W fp32 [K][1024] -> hi/lo planes, k-tiled transposed  Wt[kt][n][32].
// ---------------------------------------------------------------------------
struct WSplitArgs {
    const float* src[6];
    u16* hi[6];
    u16* lo[6];
};

__global__ __launch_bounds__(256) void split_weight_all(WSplitArgs args)
{
    const int z = blockIdx.z;
    int which, zz = 0;
    if (z < 3)       { which = z; }
    else if (z < 11) { which = 3; zz = z - 3; }
    else             { which = z - 7; }          // 4 = enc, 5 = dec
    const int KT = (which == 4) ? 17 : (which == 5 ? 3 : 32);
    const int kt = blockIdx.x;
    if (kt >= KT) return;
    const int K = KT * 32;
    const long long zoff = (long long)zz * K * 1024;
    const float* W  = args.src[which] + zoff;
    u16* hi = args.hi[which] + zoff;
    u16* lo = args.lo[which] + zoff;

    const int n0  = blockIdx.y * 128;
    const int tid = threadIdx.x;
    const int k   = tid >> 3;            // 0..31
    const int ng  = (tid & 7) * 16;      // 0,16,...,112
    const float* src = W + (long long)(kt * 32 + k) * 1024 + n0 + ng;
    u16* dh = hi + ((long long)kt * 1024 + n0) * 32 + k;
    u16* dl = lo + ((long long)kt * 1024 + n0) * 32 + k;
#pragma unroll
    for (int t = 0; t < 4; t++) {
        const float4 v = *(const float4*)(src + t * 4);
        u16 h0, l0, h1, l1, h2, l2, h3, l3;
        split1(v.x, h0, l0); split1(v.y, h1, l1);
        split1(v.z, h2, l2); split1(v.w, h3, l3);
        const int nb = (ng + t * 4) * 32;
        dh[nb]      = h0; dl[nb]      = l0;
        dh[nb + 32] = h1; dl[nb + 32] = l1;
        dh[nb + 64] = h2; dl[nb + 64] = l2;
        dh[nb + 96] = h3; dl[nb + 96] = l3;
    }
}

// ===========================================================================
// Shared MFMA quadrant cluster: 24 MFMAs (8 hh, 8 hl, 8 lh), setprio-wrapped.
// acc rows IB..IB+3, cols JB..JB+1; consumes ah/al[0..3], bh/bl[JB..JB+1].
// ===========================================================================
#define MFMA_Q(IB, JB) \
    __builtin_amdgcn_s_setprio(1); \
    _Pragma("unroll") \
    for (int i_ = 0; i_ < 4; i_++) \
        _Pragma("unroll") \
        for (int j_ = 0; j_ < 2; j_++) \
            acc[(IB) + i_][(JB) + j_] = __builtin_amdgcn_mfma_f32_16x16x32_bf16(ah[i_], bh[(JB) + j_], acc[(IB) + i_][(JB) + j_], 0, 0, 0); \
    _Pragma("unroll") \
    for (int i_ = 0; i_ < 4; i_++) \
        _Pragma("unroll") \
        for (int j_ = 0; j_ < 2; j_++) \
            acc[(IB) + i_][(JB) + j_] = __builtin_amdgcn_mfma_f32_16x16x32_bf16(ah[i_], bl[(JB) + j_], acc[(IB) + i_][(JB) + j_], 0, 0, 0); \
    _Pragma("unroll") \
    for (int i_ = 0; i_ < 4; i_++) \
        _Pragma("unroll") \
        for (int j_ = 0; j_ < 2; j_++) \
            acc[(IB) + i_][(JB) + j_] = __builtin_amdgcn_mfma_f32_16x16x32_bf16(al[i_], bh[(JB) + j_], acc[(IB) + i_][(JB) + j_], 0, 0, 0); \
    __builtin_amdgcn_s_setprio(0);

#define SBAR() \
    __builtin_amdgcn_s_barrier(); \
    __builtin_amdgcn_sched_barrier(0);

// ===========================================================================
// GEMM fast path: 256x128 tile, 8 waves (4M x 2N, per-wave 64x64), all four
// planes staged via gld16 into ring of 3 x 48 KiB (144 KiB LDS).
// Ring buffer (24576 shorts): Ah 0 (256x32), Al 8192, Bh 16384 (128x32),
// Bl 20480.  6 gld16/wave/tile, staged 2 tiles ahead, counted vmcnt(6) at
// tile boundary (never 0 mid-loop).  2 quadrant-phases/tile (24 MFMA each).
// ===========================================================================
#define G_GEOM \
    const int tid  = threadIdx.x; \
    const int lane = tid & 63; \
    const int wv   = tid >> 6; \
    const int wm   = wv >> 1, wn = wv & 1; \
    const int fr   = lane & 15; \
    const int fq   = lane >> 4; \
    const int m0   = blockIdx.y * 256; \
    const int n0   = blockIdx.x * 128; \
    const int lro2 = (lane >> 2) * 32 + (((lane & 3) ^ ((lane >> 3) & 3)) * 8); \
    const int fqx2 = (fq ^ ((fr >> 1) & 3)) * 8; \
    const int wrA  = wv * 32; \
    const int wrB  = wv * 16;

#define G_STAGE_A(buf_, t_) { \
    u16* d_ = (buf_); \
    const long long ao_ = abase + (long long)(t_) * astep; \
    gld16(Ahp + ao_ + (long long)wrA * 32 + lro2, d_ + wrA * 32); \
    gld16(Ahp + ao_ + (long long)(wrA + 16) * 32 + lro2, d_ + (wrA + 16) * 32); \
    gld16(Alp + ao_ + (long long)wrA * 32 + lro2, d_ + 8192 + wrA * 32); \
    gld16(Alp + ao_ + (long long)(wrA + 16) * 32 + lro2, d_ + 8192 + (wrA + 16) * 32); }

#define G_STAGE_B(buf_, t_) { \
    u16* d_ = (buf_); \
    const long long bo_ = bbase + (long long)(t_) * 32768; \
    gld16(Bhp + bo_ + (long long)wrB * 32 + lro2, d_ + 16384 + wrB * 32); \
    gld16(Blp + bo_ + (long long)wrB * 32 + lro2, d_ + 20480 + wrB * 32); }

#define G_RD_A(bp_) \
    _Pragma("unroll") \
    for (int i_ = 0; i_ < 4; i_++) { \
        const int off_ = (wm * 64 + i_ * 16 + fr) * 32 + fqx2; \
        ah[i_] = *(const bf16x8*)((bp_) + off_); \
        al[i_] = *(const bf16x8*)((bp_) + 8192 + off_); }

#define G_RD_B(bp_, JB) \
    _Pragma("unroll") \
    for (int j_ = 0; j_ < 2; j_++) { \
        const int off_ = (wn * 64 + ((JB) + j_) * 16 + fr) * 32 + fqx2; \
        bh[(JB) + j_] = *(const bf16x8*)((bp_) + 16384 + off_); \
        bl[(JB) + j_] = *(const bf16x8*)((bp_) + 20480 + off_); }

#define G_LOOP \
    const int KT = K >> 5; \
    const long long astep = (long long)MA * 32; \
    const long long abase = ((long long)moff + m0) * 32; \
    const long long bbase = (long long)n0 * 32; \
    G_STAGE_A(smem, 0); G_STAGE_B(smem, 0); \
    G_STAGE_A(smem + 24576, 1); G_STAGE_B(smem + 24576, 1); \
    asm volatile("s_waitcnt vmcnt(6)" ::: "memory"); \
    SBAR() \
    for (int t = 0; t < KT; t++) { \
        const u16* bp = smem + (t % 3) * 24576; \
        u16* nb = smem + ((t + 2) % 3) * 24576; \
        const bool more = (t + 2 < KT); \
        bf16x8 ah[4], al[4], bh[4], bl[4]; \
        G_RD_A(bp) \
        G_RD_B(bp, 0) \
        if (more) G_STAGE_A(nb, t + 2); \
        __builtin_amdgcn_sched_barrier(0); \
        MFMA_Q(0, 0) \
        SBAR() \
        G_RD_B(bp, 2) \
        if (more) G_STAGE_B(nb, t + 2); \
        __builtin_amdgcn_sched_barrier(0); \
        MFMA_Q(0, 2) \
        if (more) { asm volatile("s_waitcnt vmcnt(6)" ::: "memory"); } \
        else      { asm volatile("s_waitcnt vmcnt(0)" ::: "memory"); } \
        SBAR() \
    }

template <int RELU, int OUTP>
__global__ __launch_bounds__(512, 2) void gemm_fast(
    const u16* __restrict__ Ahp, const u16* __restrict__ Alp, int MA, int moff,
    const u16* __restrict__ Bhp, const u16* __restrict__ Blp,
    const float* __restrict__ bias,
    float* __restrict__ Cf,
    u16* __restrict__ Chp, u16* __restrict__ Clp, int MC,
    int K)
{
    __shared__ alignas(16) u16 smem[3 * 24576];
    G_GEOM

    f32x4 acc[4][4];
#pragma unroll
    for (int i = 0; i < 4; i++)
#pragma unroll
        for (int j = 0; j < 4; j++) acc[i][j] = 0;

    G_LOOP

#pragma unroll
    for (int j = 0; j < 4; j++) {
        const int n = n0 + wn * 64 + j * 16 + fr;
        const float bb = bias[n];
#pragma unroll
        for (int i = 0; i < 4; i++) {
#pragma unroll
            for (int r = 0; r < 4; r++) {
                const int m = m0 + wm * 64 + i * 16 + fq * 4 + r;
                float v = acc[i][j][r] + bb;
                if (RELU) v = fmaxf(v, 0.0f);
                if (OUTP) {
                    u16 h, l;
                    split1(v, h, l);
                    const long long d = ((long long)(n >> 5) * MC + moff + m) * 32 + (n & 31);
                    Chp[d] = h;
                    Clp[d] = l;
                } else {
                    Cf[(long long)m * 1024 + n] = v;
                }
            }
        }
    }
}

// ===========================================================================
// Heads: 256x256 tile per head, 8 waves (2M x 4N, per-wave 128x64).
// LDS ring of 2 x 64 KiB (128 KiB).  Buffer (32768 shorts): Ah 0 (256x32),
// Al 8192, Bh 16384 (256x32), Bl 24576.  8 gld16/wave/tile issued in phases
// 1-2; tile-boundary vmcnt(0) lands >=2 phases later (~free).
// 4 quadrant-phases/tile of 24 MFMA.  Grid (4, BC/256, 8) = 256 blocks.
// ===========================================================================
#define H_STAGE_A(buf_, t_) { \
    u16* d_ = (buf_); \
    const long long ao_ = abase + (long long)(t_) * astep; \
    gld16(Ahp + ao_ + (long long)wrA * 32 + lro2, d_ + wrA * 32); \
    gld16(Ahp + ao_ + (long long)(wrA + 16) * 32 + lro2, d_ + (wrA + 16) * 32); \
    gld16(Alp + ao_ + (long long)wrA * 32 + lro2, d_ + 8192 + wrA * 32); \
    gld16(Alp + ao_ + (long long)(wrA + 16) * 32 + lro2, d_ + 8192 + (wrA + 16) * 32); }

#define H_STAGE_B(buf_, t_) { \
    u16* d_ = (buf_); \
    const long long bo_ = bbase + (long long)(t_) * 32768; \
    gld16(Bhp + bo_ + (long long)wrA * 32 + lro2, d_ + 16384 + wrA * 32); \
    gld16(Bhp + bo_ + (long long)(wrA + 16) * 32 + lro2, d_ + 16384 + (wrA + 16) * 32); \
    gld16(Blp + bo_ + (long long)wrA * 32 + lro2, d_ + 24576 + wrA * 32); \
    gld16(Blp + bo_ + (long long)(wrA + 16) * 32 + lro2, d_ + 24576 + (wrA + 16) * 32); }

#define H_RD_A(bp_, RB) \
    _Pragma("unroll") \
    for (int i_ = 0; i_ < 4; i_++) { \
        const int off_ = ((RB) + i_ * 16 + fr) * 32 + fqx2; \
        ah[i_] = *(const bf16x8*)((bp_) + off_); \
        al[i_] = *(const bf16x8*)((bp_) + 8192 + off_); }

#define H_RD_B(bp_, JB) \
    _Pragma("unroll") \
    for (int j_ = 0; j_ < 2; j_++) { \
        const int off_ = (wn * 64 + ((JB) + j_) * 16 + fr) * 32 + fqx2; \
        bh[(JB) + j_] = *(const bf16x8*)((bp_) + 16384 + off_); \
        bl[(JB) + j_] = *(const bf16x8*)((bp_) + 24576 + off_); }

__global__ __launch_bounds__(512, 2) void heads_kernel(
    const u16* __restrict__ Ahp, const u16* __restrict__ Alp, int MA, int moff,
    const u16* __restrict__ Whp, const u16* __restrict__ Wlp,
    const float* __restrict__ b_heads,
    const float* __restrict__ decH,      // chunk-local [BC][1024]
    __half* __restrict__ headsb,         // [BC][8][1024]
    float* __restrict__ scoresp)         // [32][BC]
{
    __shared__ alignas(16) u16 smem[2 * 32768];
    __shared__ float scred[4][256];
    const int tid  = threadIdx.x;
    const int lane = tid & 63;
    const int wv   = tid >> 6;       // 0..7
    const int wm   = wv >> 2;        // 0..1 (128-row half)
    const int wn   = wv & 3;         // 0..3 (64-col quarter)
    const int fr   = lane & 15;
    const int fq   = lane >> 4;
    const int m0   = blockIdx.y * 256;
    const int n0   = blockIdx.x * 256;
    const int lro2 = (lane >> 2) * 32 + (((lane & 3) ^ ((lane >> 3) & 3)) * 8);
    const int fqx2 = (fq ^ ((fr >> 1) & 3)) * 8;
    const int wrA  = wv * 32;
    const int h = blockIdx.z;
    const u16* Bhp = Whp + (long long)h * 1048576;
    const u16* Blp = Wlp + (long long)h * 1048576;
    const float* bias = b_heads + h * 1024;

    f32x4 acc[8][4];
#pragma unroll
    for (int i = 0; i < 8; i++)
#pragma unroll
        for (int j = 0; j < 4; j++) acc[i][j] = 0;

    const long long astep = (long long)MA * 32;
    const long long abase = ((long long)moff + m0) * 32;
    const long long bbase = (long long)n0 * 32;

    H_STAGE_A(smem, 0);
    H_STAGE_B(smem, 0);
    asm volatile("s_waitcnt vmcnt(0)" ::: "memory");
    SBAR()

    for (int t = 0; t < 32; t++) {
        const u16* bp = smem + (t & 1) * 32768;
        u16* nb = smem + ((t + 1) & 1) * 32768;
        const bool more = (t + 1 < 32);
        bf16x8 ah[4], al[4], bh[4], bl[4];
        // phase 1: quadrant (0,0)
        H_RD_A(bp, wm * 128)
        H_RD_B(bp, 0)
        if (more) H_STAGE_A(nb, t + 1);
        __builtin_amdgcn_sched_barrier(0);
        MFMA_Q(0, 0)
        SBAR()
        // phase 2: quadrant (0,1)
        H_RD_B(bp, 2)
        if (more) H_STAGE_B(nb, t + 1);
        __builtin_amdgcn_sched_barrier(0);
        MFMA_Q(0, 2)
        SBAR()
        // phase 3: quadrant (1,0)
        H_RD_A(bp, wm * 128 + 64)
        __builtin_amdgcn_sched_barrier(0);
        MFMA_Q(4, 0)
        SBAR()
        // phase 4: quadrant (1,1)
        MFMA_Q(4, 2)
        asm volatile("s_waitcnt vmcnt(0)" ::: "memory");
        SBAR()
    }

    // epilogue: relu -> fp16 headsb, partial score vs decH
    float part[8][4];
#pragma unroll
    for (int i = 0; i < 8; i++)
#pragma unroll
        for (int r = 0; r < 4; r++) part[i][r] = 0.0f;

#pragma unroll
    for (int j = 0; j < 4; j++) {
        const int n = n0 + wn * 64 + j * 16 + fr;
        const float bb = bias[n];
#pragma unroll
        for (int i = 0; i < 8; i++) {
#pragma unroll
            for (int r = 0; r < 4; r++) {
                const int b_loc = m0 + wm * 128 + i * 16 + fq * 4 + r;
                const float v = fmaxf(acc[i][j][r] + bb, 0.0f);
                headsb[((long long)b_loc * HEADS + h) * 1024 + n] = __float2half(v);
                part[i][r] = fmaf(v, decH[(long long)b_loc * 1024 + n], part[i][r]);
            }
        }
    }
#pragma unroll
    for (int off = 1; off < 16; off <<= 1)
#pragma unroll
        for (int i = 0; i < 8; i++)
#pragma unroll
            for (int r = 0; r < 4; r++)
                part[i][r] += __shfl_xor(part[i][r], off, 64);

    if (fr == 0) {
#pragma unroll
        for (int i = 0; i < 8; i++)
#pragma unroll
            for (int r = 0; r < 4; r++)
                scred[wn][wm * 128 + i * 16 + fq * 4 + r] = part[i][r];
    }
    __syncthreads();
    if (tid < 256) {
        const float sv = scred[0][tid] + scred[1][tid] + scred[2][tid] + scred[3][tid];
        scoresp[(long long)(h * 4 + blockIdx.x) * BC + m0 + tid] = sv;
    }
}

// ===========================================================================
// GEMM (convert path, enc/dec): A fp32 (2-region concat), split in-kernel
// via LDS; B async from planes.  Output: hi/lo planes.
// ===========================================================================
template <int RELU>
__global__ __launch_bounds__(256) void gemm_cvt(
    const float* __restrict__ src1, int lda1, int kofs1,
    const float* __restrict__ src2, int lda2, int ksplit,
    const u16* __restrict__ Bhp, const u16* __restrict__ Blp,
    const float* __restrict__ bias,
    u16* __restrict__ Chp, u16* __restrict__ Clp, int MC,
    int K)
{
    __shared__ alignas(16) u16 Ah[4096], Al[4096], Bh[4096], Bl[4096];
    const int tid  = threadIdx.x;
    const int lane = tid & 63;
    const int wv   = tid >> 6;
    const int wm   = wv >> 1, wn = wv & 1;
    const int fr   = lane & 15;
    const int fq   = lane >> 4;
    const int m0   = blockIdx.y * 128;
    const int n0   = blockIdx.x * 128;
    const int fqx  = (fq ^ (fr & 3)) * 8;
    const int lro  = (lane >> 2) * 32 + (((lane & 3) ^ ((lane >> 2) & 3)) * 8);
    const int br0  = wv * 16;
    const int br1  = 64 + wv * 16;
    const int ar   = tid >> 3;           // 0..31
    const int akq  = tid & 7;            // float4 group 0..7
    const int awoff = (((akq >> 1) ^ (ar & 3)) * 8) + (akq & 1) * 4;

    f32x4 acc[4][4];
#pragma unroll
    for (int i = 0; i < 4; i++)
#pragma unroll
        for (int j = 0; j < 4; j++) acc[i][j] = 0;

    const int KT = K >> 5;
    for (int kt = 0; kt < KT; kt++) {
        const int k0 = kt * 32;
        const float* srcp; int ldk, kc;
        if (k0 < ksplit) { srcp = src1; ldk = lda1; kc = k0 + kofs1; }
        else             { srcp = src2; ldk = lda2; kc = k0 - ksplit; }

        const u16* Bg  = Bhp + ((long long)kt * 1024 + n0) * 32;
        const u16* Bg2 = Blp + ((long long)kt * 1024 + n0) * 32;
        gld16(Bg  + br0 * 32 + lro, &Bh[br0 * 32]);
        gld16(Bg  + br1 * 32 + lro, &Bh[br1 * 32]);
        gld16(Bg2 + br0 * 32 + lro, &Bl[br0 * 32]);
        gld16(Bg2 + br1 * 32 + lro, &Bl[br1 * 32]);

#pragma unroll
        for (int it = 0; it < 4; it++) {
            const int row = ar + it * 32;
            const float4 v = *(const float4*)(srcp + (long long)(m0 + row) * ldk + kc + akq * 4);
            uint2 hi, lo;
            splitA4(v, hi, lo);
            *(uint2*)&Ah[row * 32 + awoff] = hi;
            *(uint2*)&Al[row * 32 + awoff] = lo;
        }
        __syncthreads();

        bf16x8 ah[4], al[4], bh[4], bl[4];
#pragma unroll
        for (int i = 0; i < 4; i++) {
            const int off = (wm * 64 + i * 16 + fr) * 32 + fqx;
            ah[i] = *(const bf16x8*)&Ah[off];
            al[i] = *(const bf16x8*)&Al[off];
        }
#pragma unroll
        for (int j = 0; j < 4; j++) {
            const int off = (wn * 64 + j * 16 + fr) * 32 + fqx;
            bh[j] = *(const bf16x8*)&Bh[off];
            bl[j] = *(const bf16x8*)&Bl[off];
        }
#pragma unroll
        for (int i = 0; i < 4; i++)
#pragma unroll
            for (int j = 0; j < 4; j++) {
                acc[i][j] = __builtin_amdgcn_mfma_f32_16x16x32_bf16(ah[i], bh[j], acc[i][j], 0, 0, 0);
                acc[i][j] = __builtin_amdgcn_mfma_f32_16x16x32_bf16(ah[i], bl[j], acc[i][j], 0, 0, 0);
                acc[i][j] = __builtin_amdgcn_mfma_f32_16x16x32_bf16(al[i], bh[j], acc[i][j], 0, 0, 0);
            }
        __syncthreads();
    }

#pragma unroll
    for (int j = 0; j < 4; j++) {
        const int n = n0 + wn * 64 + j * 16 + fr;
        const float bb = bias[n];
#pragma unroll
        for (int i = 0; i < 4; i++) {
#pragma unroll
            for (int r = 0; r < 4; r++) {
                const int m = m0 + wm * 64 + i * 16 + fq * 4 + r;
                float v = acc[i][j][r] + bb;
                if (RELU) v = fmaxf(v, 0.0f);
                u16 h, l;
                split1(v, h, l);
                const long long d = ((long long)(n >> 5) * MC + m) * 32 + (n & 31);
                Chp[d] = h;
                Clp[d] = l;
            }
        }
    }
}

// ---------------------------------------------------------------------------
// context (+fused softmax): per row b, softmax over heads from scoresp
// ([32][BC]: 4 n-tiles per head), then ctx[b][d] = sum_h attn[h]*heads;
// writes hi/lo planes.
// ---------------------------------------------------------------------------
__global__ __launch_bounds__(256) void context_kernel(
    const __half* __restrict__ headsb, const float* __restrict__ scoresp,
    u16* __restrict__ ctx_hi, u16* __restrict__ ctx_lo, int MC, int row0)
{
    __shared__ float sc_s[32];
    __shared__ float attn_s[HEADS];
    const int b = blockIdx.x;
    const int tid = threadIdx.x;
    if (tid < 32) sc_s[tid] = scoresp[(long long)tid * BC + b];
    __syncthreads();
    if (tid == 0) {
        float sc[HEADS];
#pragma unroll
        for (int h = 0; h < HEADS; h++) {
            float s = 0.0f;
#pragma unroll
            for (int nt = 0; nt < 4; nt++) s += sc_s[h * 4 + nt];
            sc[h] = s;
        }
        float mx = sc[0];
#pragma unroll
        for (int h = 1; h < HEADS; h++) mx = fmaxf(mx, sc[h]);
        float e[HEADS], sum = 0.0f;
#pragma unroll
        for (int h = 0; h < HEADS; h++) { e[h] = __expf(sc[h] - mx); sum += e[h]; }
        const float inv = 1.0f / sum;
#pragma unroll
        for (int h = 0; h < HEADS; h++) attn_s[h] = e[h] * inv;
    }
    __syncthreads();

    const int d = tid * 4;
    float w[HEADS];
#pragma unroll
    for (int h = 0; h < HEADS; h++) w[h] = attn_s[h];
    float4 acc = make_float4(0.f, 0.f, 0.f, 0.f);
#pragma unroll
    for (int h = 0; h < HEADS; h++) {
        const __half2* hp = (const __half2*)(headsb + ((long long)b * HEADS + h) * 1024 + d);
        const float2 f0 = __half22float2(hp[0]);
        const float2 f1 = __half22float2(hp[1]);
        acc.x = fmaf(w[h], f0.x, acc.x);
        acc.y = fmaf(w[h], f0.y, acc.y);
        acc.z = fmaf(w[h], f1.x, acc.z);
        acc.w = fmaf(w[h], f1.y, acc.w);
    }
    uint2 hi, lo;
    splitA4(acc, hi, lo);
    const long long off = ((long long)(d >> 5) * MC + row0 + b) * 32 + (d & 31);
    *(uint2*)(ctx_hi + off) = hi;
    *(uint2*)(ctx_lo + off) = lo;
}

// ---------------------------------------------------------------------------
// fc2: q[b] = sum_d x[b,d]*W2[d] + b2[0]
// ---------------------------------------------------------------------------
__global__ __launch_bounds__(256) void fc2_kernel(
    const float* __restrict__ x, const float* __restrict__ W2,
    const float* __restrict__ b2, float* __restrict__ q)
{
    const int b   = blockIdx.x;
    const int tid = threadIdx.x;
    __shared__ float red[4];

    const float4 xv = *(const float4*)(x + (long long)b * 1024 + tid * 4);
    const float4 wv = *(const float4*)(W2 + tid * 4);
    float p = xv.x * wv.x + xv.y * wv.y + xv.z * wv.z + xv.w * wv.w;
#pragma unroll
    for (int off = 32; off > 0; off >>= 1) p += __shfl_down(p, off, 64);
    if ((tid & 63) == 0) red[tid >> 6] = p;
    __syncthreads();
    if (tid == 0) q[b] = red[0] + red[1] + red[2] + red[3] + b2[0];
}

// ---------------------------------------------------------------------------
extern "C" void kernel_launch(void* const* d_in, const int* in_sizes, int n_in,
                              void* d_out, int out_size, void* d_ws, size_t ws_size,
                              hipStream_t stream)
{
    const float* s        = (const float*)d_in[0];
    const float* a        = (const float*)d_in[1];
    const float* W_enc_in = (const float*)d_in[2];
    const float* b_enc_in = (const float*)d_in[3];
    const float* W_dec_in = (const float*)d_in[4];
    const float* b_dec_in = (const float*)d_in[5];
    const float* W_eh     = (const float*)d_in[6];
    const float* b_eh     = (const float*)d_in[7];
    const float* W_heads  = (const float*)d_in[8];
    const float* b_heads  = (const float*)d_in[9];
    const float* W_dh     = (const float*)d_in[10];
    const float* b_dh     = (const float*)d_in[11];
    const float* W1       = (const float*)d_in[12];
    const float* b1       = (const float*)d_in[13];
    const float* W2       = (const float*)d_in[14];
    const float* b2       = (const float*)d_in[15];
    float* q_out = (float*)d_out;

    // ---- weight plane layout (shorts) -------------------------------------
    u16* P = (u16*)d_ws;
    u16* enc_hi = P; P += 557056;      // 544*1024
    u16* enc_lo = P; P += 557056;
    u16* dec_hi = P; P += 98304;       // 96*1024
    u16* dec_lo = P; P += 98304;
    u16* eh_hi  = P; P += 1048576;
    u16* eh_lo  = P; P += 1048576;
    u16* dh_hi  = P; P += 1048576;
    u16* dh_lo  = P; P += 1048576;
    u16* w1_hi  = P; P += 1048576;
    u16* w1_lo  = P; P += 1048576;
    u16* wh_hi  = P; P += 8388608;     // 8*1024*1024
    u16* wh_lo  = P; P += 8388608;
    char* act = (char*)P;              // 48,758,784 bytes consumed

    const dim3 blk(256);
    const dim3 blk512(512);

    // ---- weight conversions: ONE launch -----------------------------------
    WSplitArgs wa;
    wa.src[0] = W_eh;    wa.hi[0] = eh_hi;  wa.lo[0] = eh_lo;
    wa.src[1] = W_dh;    wa.hi[1] = dh_hi;  wa.lo[1] = dh_lo;
    wa.src[2] = W1;      wa.hi[2] = w1_hi;  wa.lo[2] = w1_lo;
    wa.src[3] = W_heads; wa.hi[3] = wh_hi;  wa.lo[3] = wh_lo;
    wa.src[4] = W_enc_in; wa.hi[4] = enc_hi; wa.lo[4] = enc_lo;
    wa.src[5] = W_dec_in; wa.hi[5] = dec_hi; wa.lo[5] = dec_lo;
    split_weight_all<<<dim3(32, 8, 13), blk, 0, stream>>>(wa);

    const bool high = (ws_size >= 150011904ULL);

    if (high) {
        u16*    bufA_hi = (u16*)act;
        u16*    bufA_lo = bufA_hi + 8388608;
        __half* headsb  = (__half*)act;
        u16*    encH_hi = (u16*)(act + 33554432);
        u16*    encH_lo = encH_hi + 8388608;
        float*  decH    = (float*)(act + 2LL * 33554432);
        float*  scoresp = (float*)(act + 3LL * 33554432);

        const dim3 ggc(8, 64, 1);      // cvt kernels: 128-row tiles
        const dim3 ggf(8, 32, 1);      // gemm_fast: 256x128 tiles
        gemm_cvt<0><<<ggc, blk, 0, stream>>>(s, 512, 0, a, 128, 512,
            enc_hi, enc_lo, b_enc_in, bufA_hi, bufA_lo, 8192, 544);
        gemm_fast<1, 1><<<ggf, blk512, 0, stream>>>(bufA_hi, bufA_lo, 8192, 0,
            eh_hi, eh_lo, b_eh, nullptr, encH_hi, encH_lo, 8192, 1024);
        gemm_cvt<0><<<ggc, blk, 0, stream>>>(a, 128, 32, a, 128, 1 << 28,
            dec_hi, dec_lo, b_dec_in, bufA_hi, bufA_lo, 8192, 96);
        gemm_fast<1, 0><<<ggf, blk512, 0, stream>>>(bufA_hi, bufA_lo, 8192, 0,
            dh_hi, dh_lo, b_dh, decH, nullptr, nullptr, 0, 1024);

        for (int c = 0; c < BATCH / BC; c++) {
            heads_kernel<<<dim3(4, BC / 256, 8), blk512, 0, stream>>>(
                encH_hi, encH_lo, 8192, c * BC, wh_hi, wh_lo, b_heads,
                decH + (long long)c * BC * 1024, headsb, scoresp);
            context_kernel<<<dim3(BC), blk, 0, stream>>>(
                headsb, scoresp, encH_hi, encH_lo, 8192, c * BC);
        }
        gemm_fast<1, 0><<<ggf, blk512, 0, stream>>>(encH_hi, encH_lo, 8192, 0,
            w1_hi, w1_lo, b1, decH, nullptr, nullptr, 0, 1024);
        fc2_kernel<<<dim3(BATCH), blk, 0, stream>>>(decH, W2, b2, q_out);
    } else {
        __half* headsb  = (__half*)act;
        u16*    bufA_hi = (u16*)act;
        u16*    bufA_lo = bufA_hi + 2097152;
        u16*    encH_hi = (u16*)(act + 33554432);
        u16*    encH_lo = encH_hi + 2097152;
        float*  decH    = (float*)(act + 33554432 + 8388608);
        float*  scoresp = (float*)(act + 33554432 + 2LL * 8388608);

        const dim3 ggc(8, BC / 128, 1);
        const dim3 ggf(8, BC / 256, 1);
        for (int c = 0; c < BATCH / BC; c++) {
            const float* sC = s + (long long)c * BC * 512;
            const float* aC = a + (long long)c * BC * 128;
            gemm_cvt<0><<<ggc, blk, 0, stream>>>(sC, 512, 0, aC, 128, 512,
                enc_hi, enc_lo, b_enc_in, bufA_hi, bufA_lo, BC, 544);
            gemm_fast<1, 1><<<ggf, blk512, 0, stream>>>(bufA_hi, bufA_lo, BC, 0,
                eh_hi, eh_lo, b_eh, nullptr, encH_hi, encH_lo, BC, 1024);
            gemm_cvt<0><<<ggc, blk, 0, stream>>>(aC, 128, 32, aC, 128, 1 << 28,
                dec_hi, dec_lo, b_dec_in, bufA_hi, bufA_lo, BC, 96);
            gemm_fast<1, 0><<<ggf, blk512, 0, stream>>>(bufA_hi, bufA_lo, BC, 0,
                dh_hi, dh_lo, b_dh, decH, nullptr, nullptr, 0, 1024);
            heads_kernel<<<dim3(4, BC / 256, 8), blk512, 0, stream>>>(
                encH_hi, encH_lo, BC, 0, wh_hi, wh_lo, b_heads,
                decH, headsb, scoresp);
            context_kernel<<<dim3(BC), blk, 0, stream>>>(
                headsb, scoresp, encH_hi, encH_lo, BC, 0);
            gemm_fast<1, 0><<<ggf, blk512, 0, stream>>>(encH_hi, encH_lo, BC, 0,
                w1_hi, w1_lo, b1, decH, nullptr, nullptr, 0, 1024);
            fc2_kernel<<<dim3(BC), blk, 0, stream>>>(decH, W2, b2, q_out + (long long)c * BC);
        }
    }
}

// Round 4
// 712.401 us; speedup vs baseline: 1.1348x; 1.0547x over previous
//
#include <hip/hip_runtime.h>
#include <hip/hip_bf16.h>
#include <hip/hip_fp16.h>

#define BATCH   8192
#define HID     1024
#define HEADS   8
#define BC      2048

typedef unsigned int  u32;
typedef unsigned short u16;
typedef __attribute__((ext_vector_type(8))) short bf16x8;
typedef __attribute__((ext_vector_type(4))) float f32x4;

// ---------------------------------------------------------------------------
// hi/lo split helpers (truncation both; x = hi + lo + O(2^-16 |x|))
// ---------------------------------------------------------------------------
__device__ __forceinline__ u32 pack_hi2(u32 u0, u32 u1) {
    return (u0 >> 16) | (u1 & 0xFFFF0000u);
}
__device__ __forceinline__ void split1(float x, u16& h, u16& l) {
    const u32 u = __float_as_uint(x);
    h = (u16)(u >> 16);
    const float r = x - __uint_as_float(u & 0xFFFF0000u);
    l = (u16)(__float_as_uint(r) >> 16);
}
__device__ __forceinline__ void splitA4(float4 v, uint2& hi, uint2& lo) {
    u32 u0 = __float_as_uint(v.x), u1 = __float_as_uint(v.y),
        u2 = __float_as_uint(v.z), u3 = __float_as_uint(v.w);
    float r0 = v.x - __uint_as_float(u0 & 0xFFFF0000u);
    float r1 = v.y - __uint_as_float(u1 & 0xFFFF0000u);
    float r2 = v.z - __uint_as_float(u2 & 0xFFFF0000u);
    float r3 = v.w - __uint_as_float(u3 & 0xFFFF0000u);
    hi.x = pack_hi2(u0, u1);
    hi.y = pack_hi2(u2, u3);
    lo.x = pack_hi2(__float_as_uint(r0), __float_as_uint(r1));
    lo.y = pack_hi2(__float_as_uint(r2), __float_as_uint(r3));
}

// async global->LDS, 16 B per lane; lds base must be wave-uniform
__device__ __forceinline__ void gld16(const u16* g, u16* l) {
    __builtin_amdgcn_global_load_lds(
        (const __attribute__((address_space(1))) u32*)g,
        (__attribute__((address_space(3))) u32*)l, 16, 0, 0);
}

#define SCHED0 __builtin_amdgcn_sched_barrier(0)

// ---------------------------------------------------------------------------
// Combined weight conversion (ONE launch): 13 z-slices ->
//  z=0 eh, z=1 dh, z=2 w1, z=3..10 heads h, z=11 enc, z=12 dec
// W fp32 [K][1024] -> hi/lo planes, k-tiled transposed  Wt[kt][n][32].
// ---------------------------------------------------------------------------
struct WSplitArgs {
    const float* src[6];
    u16* hi[6];
    u16* lo[6];
};

__global__ __launch_bounds__(256) void split_weight_all(WSplitArgs args)
{
    const int z = blockIdx.z;
    int which, zz = 0;
    if (z < 3)       { which = z; }
    else if (z < 11) { which = 3; zz = z - 3; }
    else             { which = z - 7; }          // 4 = enc, 5 = dec
    const int KT = (which == 4) ? 17 : (which == 5 ? 3 : 32);
    const int kt = blockIdx.x;
    if (kt >= KT) return;
    const int K = KT * 32;
    const long long zoff = (long long)zz * K * 1024;
    const float* W  = args.src[which] + zoff;
    u16* hi = args.hi[which] + zoff;
    u16* lo = args.lo[which] + zoff;

    const int n0  = blockIdx.y * 128;
    const int tid = threadIdx.x;
    const int k   = tid >> 3;            // 0..31
    const int ng  = (tid & 7) * 16;      // 0,16,...,112
    const float* src = W + (long long)(kt * 32 + k) * 1024 + n0 + ng;
    u16* dh = hi + ((long long)kt * 1024 + n0) * 32 + k;
    u16* dl = lo + ((long long)kt * 1024 + n0) * 32 + k;
#pragma unroll
    for (int t = 0; t < 4; t++) {
        const float4 v = *(const float4*)(src + t * 4);
        u16 h0, l0, h1, l1, h2, l2, h3, l3;
        split1(v.x, h0, l0); split1(v.y, h1, l1);
        split1(v.z, h2, l2); split1(v.w, h3, l3);
        const int nb = (ng + t * 4) * 32;
        dh[nb]      = h0; dl[nb]      = l0;
        dh[nb + 32] = h1; dl[nb + 32] = l1;
        dh[nb + 64] = h2; dl[nb + 64] = l2;
        dh[nb + 96] = h3; dl[nb + 96] = l3;
    }
}

// ===========================================================================
// 24-MFMA quadrant cluster (8 hh, 8 hl, 8 lh), setprio-wrapped.
// Per-element order hh -> hl -> lh (bit-identical to previous rounds).
// ===========================================================================
#define MFMA_Q24(AH_, AL_, IB, JB) \
    __builtin_amdgcn_s_setprio(1); \
    _Pragma("unroll") \
    for (int i_ = 0; i_ < 4; i_++) \
        _Pragma("unroll") \
        for (int j_ = 0; j_ < 2; j_++) \
            acc[(IB) + i_][(JB) + j_] = __builtin_amdgcn_mfma_f32_16x16x32_bf16(AH_[i_], bh[(JB) + j_], acc[(IB) + i_][(JB) + j_], 0, 0, 0); \
    _Pragma("unroll") \
    for (int i_ = 0; i_ < 4; i_++) \
        _Pragma("unroll") \
        for (int j_ = 0; j_ < 2; j_++) \
            acc[(IB) + i_][(JB) + j_] = __builtin_amdgcn_mfma_f32_16x16x32_bf16(AH_[i_], bl[(JB) + j_], acc[(IB) + i_][(JB) + j_], 0, 0, 0); \
    _Pragma("unroll") \
    for (int i_ = 0; i_ < 4; i_++) \
        _Pragma("unroll") \
        for (int j_ = 0; j_ < 2; j_++) \
            acc[(IB) + i_][(JB) + j_] = __builtin_amdgcn_mfma_f32_16x16x32_bf16(AL_[i_], bh[(JB) + j_], acc[(IB) + i_][(JB) + j_], 0, 0, 0); \
    __builtin_amdgcn_s_setprio(0);

// ===========================================================================
// GEMM fast path: 256x128 tile, 8 waves (4M x 2N, per-wave 64x64).
// Ring of 3 x 48 KiB (144 KiB LDS); buffer (24576 shorts): Ah 0 (256x32),
// Al 8192, Bh 16384 (128x32), Bl 20480.  6 gld16/wave/tile staged 2 ahead.
// Read-ahead pipeline: fragment ds_reads issued one phase early (no wait),
// overlapping the current phase's 24-MFMA cluster.  ONE lgkmcnt(0)+vmcnt(6)
// +barrier per K-tile.  K-loop unrolled x2 with alternating A register sets
// (the ph2 prefetch would otherwise WAR-clobber live A frags).
// ===========================================================================
#define G_GEOM \
    const int tid  = threadIdx.x; \
    const int lane = tid & 63; \
    const int wv   = tid >> 6; \
    const int wm   = wv >> 1, wn = wv & 1; \
    const int m0   = blockIdx.y * 256; \
    const int n0   = blockIdx.x * 128; \
    const int fr   = lane & 15; \
    const int fq   = lane >> 4; \
    const int lro2 = (lane >> 2) * 32 + (((lane & 3) ^ ((lane >> 3) & 3)) * 8); \
    const int fqx2 = (fq ^ ((fr >> 1) & 3)) * 8; \
    const int wrA  = wv * 32; \
    const int wrB  = wv * 16;

#define G_STAGE_A(buf_, t_) { \
    u16* d_ = (buf_); \
    const long long ao_ = abase + (long long)(t_) * astep; \
    gld16(Ahp + ao_ + (long long)wrA * 32 + lro2, d_ + wrA * 32); \
    gld16(Ahp + ao_ + (long long)(wrA + 16) * 32 + lro2, d_ + (wrA + 16) * 32); \
    gld16(Alp + ao_ + (long long)wrA * 32 + lro2, d_ + 8192 + wrA * 32); \
    gld16(Alp + ao_ + (long long)(wrA + 16) * 32 + lro2, d_ + 8192 + (wrA + 16) * 32); }

#define G_STAGE_B(buf_, t_) { \
    u16* d_ = (buf_); \
    const long long bo_ = bbase + (long long)(t_) * 32768; \
    gld16(Bhp + bo_ + (long long)wrB * 32 + lro2, d_ + 16384 + wrB * 32); \
    gld16(Blp + bo_ + (long long)wrB * 32 + lro2, d_ + 20480 + wrB * 32); }

#define G_RD_A(AH_, AL_, bp_) \
    _Pragma("unroll") \
    for (int i_ = 0; i_ < 4; i_++) { \
        const int off_ = (wm * 64 + i_ * 16 + fr) * 32 + fqx2; \
        AH_[i_] = *(const bf16x8*)((bp_) + off_); \
        AL_[i_] = *(const bf16x8*)((bp_) + 8192 + off_); }

#define G_RD_B(bp_, JB) \
    _Pragma("unroll") \
    for (int j_ = 0; j_ < 2; j_++) { \
        const int off_ = (wn * 64 + ((JB) + j_) * 16 + fr) * 32 + fqx2; \
        bh[(JB) + j_] = *(const bf16x8*)((bp_) + 16384 + off_); \
        bl[(JB) + j_] = *(const bf16x8*)((bp_) + 20480 + off_); }

// one K-tile; AH_/AL_ = current A frags, NAH_/NAL_ = prefetch target set
#define G_TILE(t_, AH_, AL_, NAH_, NAL_) { \
    const u16* bp = smem + ((t_) % 3) * 24576; \
    u16* nb2 = smem + (((t_) + 2) % 3) * 24576; \
    const u16* np = smem + (((t_) + 1) % 3) * 24576; \
    const bool s_ = (t_) + 2 < KT; \
    const bool p_ = (t_) + 1 < KT; \
    G_RD_B(bp, 2) \
    if (s_) { G_STAGE_A(nb2, (t_) + 2); G_STAGE_B(nb2, (t_) + 2); } \
    SCHED0; \
    MFMA_Q24(AH_, AL_, 0, 0) \
    asm volatile("s_waitcnt lgkmcnt(0)" ::: "memory"); \
    if (s_) { asm volatile("s_waitcnt vmcnt(6)" ::: "memory"); } \
    else    { asm volatile("s_waitcnt vmcnt(0)" ::: "memory"); } \
    __builtin_amdgcn_s_barrier(); \
    SCHED0; \
    if (p_) { G_RD_A(NAH_, NAL_, np) G_RD_B(np, 0) } \
    SCHED0; \
    MFMA_Q24(AH_, AL_, 0, 2) \
    SCHED0; \
}

template <int RELU, int OUTP>
__global__ __launch_bounds__(512, 2) void gemm_fast(
    const u16* __restrict__ Ahp, const u16* __restrict__ Alp, int MA, int moff,
    const u16* __restrict__ Bhp, const u16* __restrict__ Blp,
    const float* __restrict__ bias,
    float* __restrict__ Cf,
    u16* __restrict__ Chp, u16* __restrict__ Clp, int MC,
    int K)
{
    __shared__ alignas(16) u16 smem[3 * 24576];
    G_GEOM

    f32x4 acc[4][4];
#pragma unroll
    for (int i = 0; i < 4; i++)
#pragma unroll
        for (int j = 0; j < 4; j++) acc[i][j] = 0;

    const int KT = K >> 5;
    const long long astep = (long long)MA * 32;
    const long long abase = ((long long)moff + m0) * 32;
    const long long bbase = (long long)n0 * 32;

    bf16x8 ahA[4], alA[4], ahB[4], alB[4], bh[4], bl[4];

    G_STAGE_A(smem, 0); G_STAGE_B(smem, 0);
    G_STAGE_A(smem + 24576, 1); G_STAGE_B(smem + 24576, 1);
    asm volatile("s_waitcnt vmcnt(6)" ::: "memory");
    __builtin_amdgcn_s_barrier();
    SCHED0;
    G_RD_A(ahA, alA, smem)
    G_RD_B(smem, 0)

    for (int t = 0; t < KT; t += 2) {
        G_TILE(t,     ahA, alA, ahB, alB)
        G_TILE(t + 1, ahB, alB, ahA, alA)
    }

#pragma unroll
    for (int j = 0; j < 4; j++) {
        const int n = n0 + wn * 64 + j * 16 + fr;
        const float bb = bias[n];
#pragma unroll
        for (int i = 0; i < 4; i++) {
#pragma unroll
            for (int r = 0; r < 4; r++) {
                const int m = m0 + wm * 64 + i * 16 + fq * 4 + r;
                float v = acc[i][j][r] + bb;
                if (RELU) v = fmaxf(v, 0.0f);
                if (OUTP) {
                    u16 h, l;
                    split1(v, h, l);
                    const long long d = ((long long)(n >> 5) * MC + moff + m) * 32 + (n & 31);
                    Chp[d] = h;
                    Clp[d] = l;
                } else {
                    Cf[(long long)m * 1024 + n] = v;
                }
            }
        }
    }
}

// ===========================================================================
// Heads: 256x256 tile per head, 8 waves (2M x 4N, per-wave 128x64).
// LDS ring of 2 x 64 KiB; buffer (32768 shorts): Ah 0 (256x32), Al 8192,
// Bh 16384 (256x32), Bl 24576.  Read-ahead pipeline, ONE lgkmcnt(0)+
// vmcnt(0)+barrier per K-tile (stage has 2-phase slack).  4 phases of 24
// MFMA; phase p's ds_reads issued in phase p-1.  Grid (4, BC/256, 8).
// ===========================================================================
#define H_STAGE_A(buf_, t_) { \
    u16* d_ = (buf_); \
    const long long ao_ = abase + (long long)(t_) * astep; \
    gld16(Ahp + ao_ + (long long)wrA * 32 + lro2, d_ + wrA * 32); \
    gld16(Ahp + ao_ + (long long)(wrA + 16) * 32 + lro2, d_ + (wrA + 16) * 32); \
    gld16(Alp + ao_ + (long long)wrA * 32 + lro2, d_ + 8192 + wrA * 32); \
    gld16(Alp + ao_ + (long long)(wrA + 16) * 32 + lro2, d_ + 8192 + (wrA + 16) * 32); }

#define H_STAGE_B(buf_, t_) { \
    u16* d_ = (buf_); \
    const long long bo_ = bbase + (long long)(t_) * 32768; \
    gld16(Bhp + bo_ + (long long)wrA * 32 + lro2, d_ + 16384 + wrA * 32); \
    gld16(Bhp + bo_ + (long long)(wrA + 16) * 32 + lro2, d_ + 16384 + (wrA + 16) * 32); \
    gld16(Blp + bo_ + (long long)wrA * 32 + lro2, d_ + 24576 + wrA * 32); \
    gld16(Blp + bo_ + (long long)(wrA + 16) * 32 + lro2, d_ + 24576 + (wrA + 16) * 32); }

#define H_RD_A0(bp_) \
    _Pragma("unroll") \
    for (int i_ = 0; i_ < 4; i_++) { \
        const int off_ = (wm * 128 + i_ * 16 + fr) * 32 + fqx2; \
        ah0[i_] = *(const bf16x8*)((bp_) + off_); \
        al0[i_] = *(const bf16x8*)((bp_) + 8192 + off_); }

#define H_RD_A1(bp_) \
    _Pragma("unroll") \
    for (int i_ = 0; i_ < 4; i_++) { \
        const int off_ = (wm * 128 + 64 + i_ * 16 + fr) * 32 + fqx2; \
        ah1[i_] = *(const bf16x8*)((bp_) + off_); \
        al1[i_] = *(const bf16x8*)((bp_) + 8192 + off_); }

#define H_RD_B01(bp_) \
    _Pragma("unroll") \
    for (int j_ = 0; j_ < 2; j_++) { \
        const int off_ = (wn * 64 + j_ * 16 + fr) * 32 + fqx2; \
        bh[j_] = *(const bf16x8*)((bp_) + 16384 + off_); \
        bl[j_] = *(const bf16x8*)((bp_) + 24576 + off_); }

#define H_RD_B23(bp_) \
    _Pragma("unroll") \
    for (int j_ = 0; j_ < 2; j_++) { \
        const int off_ = (wn * 64 + (2 + j_) * 16 + fr) * 32 + fqx2; \
        bh[2 + j_] = *(const bf16x8*)((bp_) + 16384 + off_); \
        bl[2 + j_] = *(const bf16x8*)((bp_) + 24576 + off_); }

__global__ __launch_bounds__(512, 2) void heads_kernel(
    const u16* __restrict__ Ahp, const u16* __restrict__ Alp, int MA, int moff,
    const u16* __restrict__ Whp, const u16* __restrict__ Wlp,
    const float* __restrict__ b_heads,
    const float* __restrict__ decH,      // chunk-local [BC][1024]
    __half* __restrict__ headsb,         // [BC][8][1024]
    float* __restrict__ scoresp)         // [32][BC]
{
    __shared__ alignas(16) u16 smem[2 * 32768];
    __shared__ float scred[4][256];
    const int tid  = threadIdx.x;
    const int lane = tid & 63;
    const int wv   = tid >> 6;       // 0..7
    const int wm   = wv >> 2;        // 0..1 (128-row half)
    const int wn   = wv & 3;         // 0..3 (64-col quarter)
    const int fr   = lane & 15;
    const int fq   = lane >> 4;
    const int m0   = blockIdx.y * 256;
    const int n0   = blockIdx.x * 256;
    const int lro2 = (lane >> 2) * 32 + (((lane & 3) ^ ((lane >> 3) & 3)) * 8);
    const int fqx2 = (fq ^ ((fr >> 1) & 3)) * 8;
    const int wrA  = wv * 32;
    const int h = blockIdx.z;
    const u16* Bhp = Whp + (long long)h * 1048576;
    const u16* Blp = Wlp + (long long)h * 1048576;
    const float* bias = b_heads + h * 1024;

    f32x4 acc[8][4];
#pragma unroll
    for (int i = 0; i < 8; i++)
#pragma unroll
        for (int j = 0; j < 4; j++) acc[i][j] = 0;

    const long long astep = (long long)MA * 32;
    const long long abase = ((long long)moff + m0) * 32;
    const long long bbase = (long long)n0 * 32;

    bf16x8 ah0[4], al0[4], ah1[4], al1[4], bh[4], bl[4];

    H_STAGE_A(smem, 0);
    H_STAGE_B(smem, 0);
    asm volatile("s_waitcnt vmcnt(0)" ::: "memory");
    __builtin_amdgcn_s_barrier();
    SCHED0;
    H_RD_A0(smem)
    H_RD_B01(smem)

    for (int t = 0; t < 32; t++) {
        const u16* bp = smem + (t & 1) * 32768;
        u16* nb = smem + ((t + 1) & 1) * 32768;
        const bool more = t < 31;
        // ph1: Q(0..3, 0..1) uses ah0,b01; read B23(this tile); stage A(t+1)
        H_RD_B23(bp)
        if (more) H_STAGE_A(nb, t + 1);
        SCHED0;
        MFMA_Q24(ah0, al0, 0, 0)
        SCHED0;
        // ph2: Q(0..3, 2..3) uses ah0,b23; read A1(this tile); stage B(t+1)
        H_RD_A1(bp)
        if (more) H_STAGE_B(nb, t + 1);
        SCHED0;
        MFMA_Q24(ah0, al0, 0, 2)
        SCHED0;
        // ph3: Q(4..7, 0..1) uses ah1,b01; then tile checkpoint
        MFMA_Q24(ah1, al1, 4, 0)
        asm volatile("s_waitcnt lgkmcnt(0)" ::: "memory");
        asm volatile("s_waitcnt vmcnt(0)" ::: "memory");
        __builtin_amdgcn_s_barrier();
        SCHED0;
        // ph4: Q(4..7, 2..3) uses ah1,b23; prefetch next tile's A0,B01
        if (more) { H_RD_A0(nb) H_RD_B01(nb) }
        SCHED0;
        MFMA_Q24(ah1, al1, 4, 2)
        SCHED0;
    }

    // epilogue: relu -> fp16 headsb, partial score vs decH
    float part[8][4];
#pragma unroll
    for (int i = 0; i < 8; i++)
#pragma unroll
        for (int r = 0; r < 4; r++) part[i][r] = 0.0f;

#pragma unroll
    for (int j = 0; j < 4; j++) {
        const int n = n0 + wn * 64 + j * 16 + fr;
        const float bb = bias[n];
#pragma unroll
        for (int i = 0; i < 8; i++) {
#pragma unroll
            for (int r = 0; r < 4; r++) {
                const int b_loc = m0 + wm * 128 + i * 16 + fq * 4 + r;
                const float v = fmaxf(acc[i][j][r] + bb, 0.0f);
                headsb[((long long)b_loc * HEADS + h) * 1024 + n] = __float2half(v);
                part[i][r] = fmaf(v, decH[(long long)b_loc * 1024 + n], part[i][r]);
            }
        }
    }
#pragma unroll
    for (int off = 1; off < 16; off <<= 1)
#pragma unroll
        for (int i = 0; i < 8; i++)
#pragma unroll
            for (int r = 0; r < 4; r++)
                part[i][r] += __shfl_xor(part[i][r], off, 64);

    if (fr == 0) {
#pragma unroll
        for (int i = 0; i < 8; i++)
#pragma unroll
            for (int r = 0; r < 4; r++)
                scred[wn][wm * 128 + i * 16 + fq * 4 + r] = part[i][r];
    }
    __syncthreads();
    if (tid < 256) {
        const float sv = scred[0][tid] + scred[1][tid] + scred[2][tid] + scred[3][tid];
        scoresp[(long long)(h * 4 + blockIdx.x) * BC + m0 + tid] = sv;
    }
}

// ===========================================================================
// GEMM (convert path, enc/dec): A fp32 (2-region concat), split in-kernel
// via LDS; B async from planes.  Output: hi/lo planes.
// ===========================================================================
template <int RELU>
__global__ __launch_bounds__(256) void gemm_cvt(
    const float* __restrict__ src1, int lda1, int kofs1,
    const float* __restrict__ src2, int lda2, int ksplit,
    const u16* __restrict__ Bhp, const u16* __restrict__ Blp,
    const float* __restrict__ bias,
    u16* __restrict__ Chp, u16* __restrict__ Clp, int MC,
    int K)
{
    __shared__ alignas(16) u16 Ah[4096], Al[4096], Bh[4096], Bl[4096];
    const int tid  = threadIdx.x;
    const int lane = tid & 63;
    const int wv   = tid >> 6;
    const int wm   = wv >> 1, wn = wv & 1;
    const int fr   = lane & 15;
    const int fq   = lane >> 4;
    const int m0   = blockIdx.y * 128;
    const int n0   = blockIdx.x * 128;
    const int fqx  = (fq ^ (fr & 3)) * 8;
    const int lro  = (lane >> 2) * 32 + (((lane & 3) ^ ((lane >> 2) & 3)) * 8);
    const int br0  = wv * 16;
    const int br1  = 64 + wv * 16;
    const int ar   = tid >> 3;           // 0..31
    const int akq  = tid & 7;            // float4 group 0..7
    const int awoff = (((akq >> 1) ^ (ar & 3)) * 8) + (akq & 1) * 4;

    f32x4 acc[4][4];
#pragma unroll
    for (int i = 0; i < 4; i++)
#pragma unroll
        for (int j = 0; j < 4; j++) acc[i][j] = 0;

    const int KT = K >> 5;
    for (int kt = 0; kt < KT; kt++) {
        const int k0 = kt * 32;
        const float* srcp; int ldk, kc;
        if (k0 < ksplit) { srcp = src1; ldk = lda1; kc = k0 + kofs1; }
        else             { srcp = src2; ldk = lda2; kc = k0 - ksplit; }

        const u16* Bg  = Bhp + ((long long)kt * 1024 + n0) * 32;
        const u16* Bg2 = Blp + ((long long)kt * 1024 + n0) * 32;
        gld16(Bg  + br0 * 32 + lro, &Bh[br0 * 32]);
        gld16(Bg  + br1 * 32 + lro, &Bh[br1 * 32]);
        gld16(Bg2 + br0 * 32 + lro, &Bl[br0 * 32]);
        gld16(Bg2 + br1 * 32 + lro, &Bl[br1 * 32]);

#pragma unroll
        for (int it = 0; it < 4; it++) {
            const int row = ar + it * 32;
            const float4 v = *(const float4*)(srcp + (long long)(m0 + row) * ldk + kc + akq * 4);
            uint2 hi, lo;
            splitA4(v, hi, lo);
            *(uint2*)&Ah[row * 32 + awoff] = hi;
            *(uint2*)&Al[row * 32 + awoff] = lo;
        }
        __syncthreads();

        bf16x8 ah[4], al[4], bh[4], bl[4];
#pragma unroll
        for (int i = 0; i < 4; i++) {
            const int off = (wm * 64 + i * 16 + fr) * 32 + fqx;
            ah[i] = *(const bf16x8*)&Ah[off];
            al[i] = *(const bf16x8*)&Al[off];
        }
#pragma unroll
        for (int j = 0; j < 4; j++) {
            const int off = (wn * 64 + j * 16 + fr) * 32 + fqx;
            bh[j] = *(const bf16x8*)&Bh[off];
            bl[j] = *(const bf16x8*)&Bl[off];
        }
#pragma unroll
        for (int i = 0; i < 4; i++)
#pragma unroll
            for (int j = 0; j < 4; j++) {
                acc[i][j] = __builtin_amdgcn_mfma_f32_16x16x32_bf16(ah[i], bh[j], acc[i][j], 0, 0, 0);
                acc[i][j] = __builtin_amdgcn_mfma_f32_16x16x32_bf16(ah[i], bl[j], acc[i][j], 0, 0, 0);
                acc[i][j] = __builtin_amdgcn_mfma_f32_16x16x32_bf16(al[i], bh[j], acc[i][j], 0, 0, 0);
            }
        __syncthreads();
    }

#pragma unroll
    for (int j = 0; j < 4; j++) {
        const int n = n0 + wn * 64 + j * 16 + fr;
        const float bb = bias[n];
#pragma unroll
        for (int i = 0; i < 4; i++) {
#pragma unroll
            for (int r = 0; r < 4; r++) {
                const int m = m0 + wm * 64 + i * 16 + fq * 4 + r;
                float v = acc[i][j][r] + bb;
                if (RELU) v = fmaxf(v, 0.0f);
                u16 h, l;
                split1(v, h, l);
                const long long d = ((long long)(n >> 5) * MC + m) * 32 + (n & 31);
                Chp[d] = h;
                Clp[d] = l;
            }
        }
    }
}

// ---------------------------------------------------------------------------
// context (+fused softmax): per row b, softmax over heads from scoresp
// ([32][BC]: 4 n-tiles per head), then ctx[b][d] = sum_h attn[h]*heads;
// writes hi/lo planes.
// ---------------------------------------------------------------------------
__global__ __launch_bounds__(256) void context_kernel(
    const __half* __restrict__ headsb, const float* __restrict__ scoresp,
    u16* __restrict__ ctx_hi, u16* __restrict__ ctx_lo, int MC, int row0)
{
    __shared__ float sc_s[32];
    __shared__ float attn_s[HEADS];
    const int b = blockIdx.x;
    const int tid = threadIdx.x;
    if (tid < 32) sc_s[tid] = scoresp[(long long)tid * BC + b];
    __syncthreads();
    if (tid == 0) {
        float sc[HEADS];
#pragma unroll
        for (int h = 0; h < HEADS; h++) {
            float s = 0.0f;
#pragma unroll
            for (int nt = 0; nt < 4; nt++) s += sc_s[h * 4 + nt];
            sc[h] = s;
        }
        float mx = sc[0];
#pragma unroll
        for (int h = 1; h < HEADS; h++) mx = fmaxf(mx, sc[h]);
        float e[HEADS], sum = 0.0f;
#pragma unroll
        for (int h = 0; h < HEADS; h++) { e[h] = __expf(sc[h] - mx); sum += e[h]; }
        const float inv = 1.0f / sum;
#pragma unroll
        for (int h = 0; h < HEADS; h++) attn_s[h] = e[h] * inv;
    }
    __syncthreads();

    const int d = tid * 4;
    float w[HEADS];
#pragma unroll
    for (int h = 0; h < HEADS; h++) w[h] = attn_s[h];
    float4 acc = make_float4(0.f, 0.f, 0.f, 0.f);
#pragma unroll
    for (int h = 0; h < HEADS; h++) {
        const __half2* hp = (const __half2*)(headsb + ((long long)b * HEADS + h) * 1024 + d);
        const float2 f0 = __half22float2(hp[0]);
        const float2 f1 = __half22float2(hp[1]);
        acc.x = fmaf(w[h], f0.x, acc.x);
        acc.y = fmaf(w[h], f0.y, acc.y);
        acc.z = fmaf(w[h], f1.x, acc.z);
        acc.w = fmaf(w[h], f1.y, acc.w);
    }
    uint2 hi, lo;
    splitA4(acc, hi, lo);
    const long long off = ((long long)(d >> 5) * MC + row0 + b) * 32 + (d & 31);
    *(uint2*)(ctx_hi + off) = hi;
    *(uint2*)(ctx_lo + off) = lo;
}

// ---------------------------------------------------------------------------
// fc2: q[b] = sum_d x[b,d]*W2[d] + b2[0]
// ---------------------------------------------------------------------------
__global__ __launch_bounds__(256) void fc2_kernel(
    const float* __restrict__ x, const float* __restrict__ W2,
    const float* __restrict__ b2, float* __restrict__ q)
{
    const int b   = blockIdx.x;
    const int tid = threadIdx.x;
    __shared__ float red[4];

    const float4 xv = *(const float4*)(x + (long long)b * 1024 + tid * 4);
    const float4 wv = *(const float4*)(W2 + tid * 4);
    float p = xv.x * wv.x + xv.y * wv.y + xv.z * wv.z + xv.w * wv.w;
#pragma unroll
    for (int off = 32; off > 0; off >>= 1) p += __shfl_down(p, off, 64);
    if ((tid & 63) == 0) red[tid >> 6] = p;
    __syncthreads();
    if (tid == 0) q[b] = red[0] + red[1] + red[2] + red[3] + b2[0];
}

// ---------------------------------------------------------------------------
extern "C" void kernel_launch(void* const* d_in, const int* in_sizes, int n_in,
                              void* d_out, int out_size, void* d_ws, size_t ws_size,
                              hipStream_t stream)
{
    const float* s        = (const float*)d_in[0];
    const float* a        = (const float*)d_in[1];
    const float* W_enc_in = (const float*)d_in[2];
    const float* b_enc_in = (const float*)d_in[3];
    const float* W_dec_in = (const float*)d_in[4];
    const float* b_dec_in = (const float*)d_in[5];
    const float* W_eh     = (const float*)d_in[6];
    const float* b_eh     = (const float*)d_in[7];
    const float* W_heads  = (const float*)d_in[8];
    const float* b_heads  = (const float*)d_in[9];
    const float* W_dh     = (const float*)d_in[10];
    const float* b_dh     = (const float*)d_in[11];
    const float* W1       = (const float*)d_in[12];
    const float* b1       = (const float*)d_in[13];
    const float* W2       = (const float*)d_in[14];
    const float* b2       = (const float*)d_in[15];
    float* q_out = (float*)d_out;

    // ---- weight plane layout (shorts) -------------------------------------
    u16* P = (u16*)d_ws;
    u16* enc_hi = P; P += 557056;      // 544*1024
    u16* enc_lo = P; P += 557056;
    u16* dec_hi = P; P += 98304;       // 96*1024
    u16* dec_lo = P; P += 98304;
    u16* eh_hi  = P; P += 1048576;
    u16* eh_lo  = P; P += 1048576;
    u16* dh_hi  = P; P += 1048576;
    u16* dh_lo  = P; P += 1048576;
    u16* w1_hi  = P; P += 1048576;
    u16* w1_lo  = P; P += 1048576;
    u16* wh_hi  = P; P += 8388608;     // 8*1024*1024
    u16* wh_lo  = P; P += 8388608;
    char* act = (char*)P;              // 48,758,784 bytes consumed

    const dim3 blk(256);
    const dim3 blk512(512);

    // ---- weight conversions: ONE launch -----------------------------------
    WSplitArgs wa;
    wa.src[0] = W_eh;    wa.hi[0] = eh_hi;  wa.lo[0] = eh_lo;
    wa.src[1] = W_dh;    wa.hi[1] = dh_hi;  wa.lo[1] = dh_lo;
    wa.src[2] = W1;      wa.hi[2] = w1_hi;  wa.lo[2] = w1_lo;
    wa.src[3] = W_heads; wa.hi[3] = wh_hi;  wa.lo[3] = wh_lo;
    wa.src[4] = W_enc_in; wa.hi[4] = enc_hi; wa.lo[4] = enc_lo;
    wa.src[5] = W_dec_in; wa.hi[5] = dec_hi; wa.lo[5] = dec_lo;
    split_weight_all<<<dim3(32, 8, 13), blk, 0, stream>>>(wa);

    const bool high = (ws_size >= 150011904ULL);

    if (high) {
        u16*    bufA_hi = (u16*)act;
        u16*    bufA_lo = bufA_hi + 8388608;
        __half* headsb  = (__half*)act;
        u16*    encH_hi = (u16*)(act + 33554432);
        u16*    encH_lo = encH_hi + 8388608;
        float*  decH    = (float*)(act + 2LL * 33554432);
        float*  scoresp = (float*)(act + 3LL * 33554432);

        const dim3 ggc(8, 64, 1);      // cvt kernels: 128-row tiles
        const dim3 ggf(8, 32, 1);      // gemm_fast: 256x128 tiles
        gemm_cvt<0><<<ggc, blk, 0, stream>>>(s, 512, 0, a, 128, 512,
            enc_hi, enc_lo, b_enc_in, bufA_hi, bufA_lo, 8192, 544);
        gemm_fast<1, 1><<<ggf, blk512, 0, stream>>>(bufA_hi, bufA_lo, 8192, 0,
            eh_hi, eh_lo, b_eh, nullptr, encH_hi, encH_lo, 8192, 1024);
        gemm_cvt<0><<<ggc, blk, 0, stream>>>(a, 128, 32, a, 128, 1 << 28,
            dec_hi, dec_lo, b_dec_in, bufA_hi, bufA_lo, 8192, 96);
        gemm_fast<1, 0><<<ggf, blk512, 0, stream>>>(bufA_hi, bufA_lo, 8192, 0,
            dh_hi, dh_lo, b_dh, decH, nullptr, nullptr, 0, 1024);

        for (int c = 0; c < BATCH / BC; c++) {
            heads_kernel<<<dim3(4, BC / 256, 8), blk512, 0, stream>>>(
                encH_hi, encH_lo, 8192, c * BC, wh_hi, wh_lo, b_heads,
                decH + (long long)c * BC * 1024, headsb, scoresp);
            context_kernel<<<dim3(BC), blk, 0, stream>>>(
                headsb, scoresp, encH_hi, encH_lo, 8192, c * BC);
        }
        gemm_fast<1, 0><<<ggf, blk512, 0, stream>>>(encH_hi, encH_lo, 8192, 0,
            w1_hi, w1_lo, b1, decH, nullptr, nullptr, 0, 1024);
        fc2_kernel<<<dim3(BATCH), blk, 0, stream>>>(decH, W2, b2, q_out);
    } else {
        __half* headsb  = (__half*)act;
        u16*    bufA_hi = (u16*)act;
        u16*    bufA_lo = bufA_hi + 2097152;
        u16*    encH_hi = (u16*)(act + 33554432);
        u16*    encH_lo = encH_hi + 2097152;
        float*  decH    = (float*)(act + 33554432 + 8388608);
        float*  scoresp = (float*)(act + 33554432 + 2LL * 8388608);

        const dim3 ggc(8, BC / 128, 1);
        const dim3 ggf(8, BC / 256, 1);
        for (int c = 0; c < BATCH / BC; c++) {
            const float* sC = s + (long long)c * BC * 512;
            const float* aC = a + (long long)c * BC * 128;
            gemm_cvt<0><<<ggc, blk, 0, stream>>>(sC, 512, 0, aC, 128, 512,
                enc_hi, enc_lo, b_enc_in, bufA_hi, bufA_lo, BC, 544);
            gemm_fast<1, 1><<<ggf, blk512, 0, stream>>>(bufA_hi, bufA_lo, BC, 0,
                eh_hi, eh_lo, b_eh, nullptr, encH_hi, encH_lo, BC, 1024);
            gemm_cvt<0><<<ggc, blk, 0, stream>>>(aC, 128, 32, aC, 128, 1 << 28,
                dec_hi, dec_lo, b_dec_in, bufA_hi, bufA_lo, BC, 96);
            gemm_fast<1, 0><<<ggf, blk512, 0, stream>>>(bufA_hi, bufA_lo, BC, 0,
                dh_hi, dh_lo, b_dh, decH, nullptr, nullptr, 0, 1024);
            heads_kernel<<<dim3(4, BC / 256, 8), blk512, 0, stream>>>(
                encH_hi, encH_lo, BC, 0, wh_hi, wh_lo, b_heads,
                decH, headsb, scoresp);
            context_kernel<<<dim3(BC), blk, 0, stream>>>(
                headsb, scoresp, encH_hi, encH_lo, BC, 0);
            gemm_fast<1, 0><<<ggf, blk512, 0, stream>>>(encH_hi, encH_lo, BC, 0,
                w1_hi, w1_lo, b1, decH, nullptr, nullptr, 0, 1024);
            fc2_kernel<<<dim3(BC), blk, 0, stream>>>(decH, W2, b2, q_out + (long long)c * BC);
        }
    }
}

// Round 6
// 696.926 us; speedup vs baseline: 1.1600x; 1.0222x over previous
//
#include <hip/hip_runtime.h>
#include <hip/hip_bf16.h>
#include <hip/hip_fp16.h>

#define BATCH   8192
#define HID     1024
#define HEADS   8
#define BC      2048

typedef unsigned int  u32;
typedef unsigned short u16;
typedef __attribute__((ext_vector_type(8))) short bf16x8;
typedef __attribute__((ext_vector_type(4))) float f32x4;

// ---------------------------------------------------------------------------
// hi/lo split helpers (truncation both; x = hi + lo + O(2^-16 |x|))
// ---------------------------------------------------------------------------
__device__ __forceinline__ u32 pack_hi2(u32 u0, u32 u1) {
    return (u0 >> 16) | (u1 & 0xFFFF0000u);
}
__device__ __forceinline__ void split1(float x, u16& h, u16& l) {
    const u32 u = __float_as_uint(x);
    h = (u16)(u >> 16);
    const float r = x - __uint_as_float(u & 0xFFFF0000u);
    l = (u16)(__float_as_uint(r) >> 16);
}
__device__ __forceinline__ void splitA4(float4 v, uint2& hi, uint2& lo) {
    u32 u0 = __float_as_uint(v.x), u1 = __float_as_uint(v.y),
        u2 = __float_as_uint(v.z), u3 = __float_as_uint(v.w);
    float r0 = v.x - __uint_as_float(u0 & 0xFFFF0000u);
    float r1 = v.y - __uint_as_float(u1 & 0xFFFF0000u);
    float r2 = v.z - __uint_as_float(u2 & 0xFFFF0000u);
    float r3 = v.w - __uint_as_float(u3 & 0xFFFF0000u);
    hi.x = pack_hi2(u0, u1);
    hi.y = pack_hi2(u2, u3);
    lo.x = pack_hi2(__float_as_uint(r0), __float_as_uint(r1));
    lo.y = pack_hi2(__float_as_uint(r2), __float_as_uint(r3));
}

// async global->LDS, 16 B per lane; lds base must be wave-uniform
__device__ __forceinline__ void gld16(const u16* g, u16* l) {
    __builtin_amdgcn_global_load_lds(
        (const __attribute__((address_space(1))) u32*)g,
        (__attribute__((address_space(3))) u32*)l, 16, 0, 0);
}

#define SCHED0 __builtin_amdgcn_sched_barrier(0)

// ---------------------------------------------------------------------------
// Combined weight conversion (ONE launch): 13 z-slices ->
//  z=0 eh, z=1 dh, z=2 w1, z=3..10 heads h, z=11 enc, z=12 dec
// W fp32 [K][1024] -> hi/lo planes, k-tiled transposed  Wt[kt][n][32].
// ---------------------------------------------------------------------------
struct WSplitArgs {
    const float* src[6];
    u16* hi[6];
    u16* lo[6];
};

__global__ __launch_bounds__(256) void split_weight_all(WSplitArgs args)
{
    const int z = blockIdx.z;
    int which, zz = 0;
    if (z < 3)       { which = z; }
    else if (z < 11) { which = 3; zz = z - 3; }
    else             { which = z - 7; }          // 4 = enc, 5 = dec
    const int KT = (which == 4) ? 17 : (which == 5 ? 3 : 32);
    const int kt = blockIdx.x;
    if (kt >= KT) return;
    const int K = KT * 32;
    const long long zoff = (long long)zz * K * 1024;
    const float* W  = args.src[which] + zoff;
    u16* hi = args.hi[which] + zoff;
    u16* lo = args.lo[which] + zoff;

    const int n0  = blockIdx.y * 128;
    const int tid = threadIdx.x;
    const int k   = tid >> 3;            // 0..31
    const int ng  = (tid & 7) * 16;      // 0,16,...,112
    const float* src = W + (long long)(kt * 32 + k) * 1024 + n0 + ng;
    u16* dh = hi + ((long long)kt * 1024 + n0) * 32 + k;
    u16* dl = lo + ((long long)kt * 1024 + n0) * 32 + k;
#pragma unroll
    for (int t = 0; t < 4; t++) {
        const float4 v = *(const float4*)(src + t * 4);
        u16 h0, l0, h1, l1, h2, l2, h3, l3;
        split1(v.x, h0, l0); split1(v.y, h1, l1);
        split1(v.z, h2, l2); split1(v.w, h3, l3);
        const int nb = (ng + t * 4) * 32;
        dh[nb]      = h0; dl[nb]      = l0;
        dh[nb + 32] = h1; dl[nb + 32] = l1;
        dh[nb + 64] = h2; dl[nb + 64] = l2;
        dh[nb + 96] = h3; dl[nb + 96] = l3;
    }
}

// ===========================================================================
// 24-MFMA quadrant cluster (8 hh, 8 hl, 8 lh), setprio-wrapped.
// Per-element order hh -> hl -> lh (bit-identical to previous rounds).
// ===========================================================================
#define MFMA_Q24(AH_, AL_, IB, JB) \
    __builtin_amdgcn_s_setprio(1); \
    _Pragma("unroll") \
    for (int i_ = 0; i_ < 4; i_++) \
        _Pragma("unroll") \
        for (int j_ = 0; j_ < 2; j_++) \
            acc[(IB) + i_][(JB) + j_] = __builtin_amdgcn_mfma_f32_16x16x32_bf16(AH_[i_], bh[(JB) + j_], acc[(IB) + i_][(JB) + j_], 0, 0, 0); \
    _Pragma("unroll") \
    for (int i_ = 0; i_ < 4; i_++) \
        _Pragma("unroll") \
        for (int j_ = 0; j_ < 2; j_++) \
            acc[(IB) + i_][(JB) + j_] = __builtin_amdgcn_mfma_f32_16x16x32_bf16(AH_[i_], bl[(JB) + j_], acc[(IB) + i_][(JB) + j_], 0, 0, 0); \
    _Pragma("unroll") \
    for (int i_ = 0; i_ < 4; i_++) \
        _Pragma("unroll") \
        for (int j_ = 0; j_ < 2; j_++) \
            acc[(IB) + i_][(JB) + j_] = __builtin_amdgcn_mfma_f32_16x16x32_bf16(AL_[i_], bh[(JB) + j_], acc[(IB) + i_][(JB) + j_], 0, 0, 0); \
    __builtin_amdgcn_s_setprio(0);

// ===========================================================================
// GEMM fast path: 256x128 tile, 8 waves (4M x 2N, per-wave 64x64).
// Ring of 3 x 48 KiB; read-ahead pipeline (frag ds_reads one phase early),
// ONE lgkmcnt(0)+vmcnt(6)+barrier per K-tile, K-loop unrolled x2 with
// alternating A register sets.
// ===========================================================================
#define G_GEOM \
    const int tid  = threadIdx.x; \
    const int lane = tid & 63; \
    const int wv   = tid >> 6; \
    const int wm   = wv >> 1, wn = wv & 1; \
    const int m0   = blockIdx.y * 256; \
    const int n0   = blockIdx.x * 128; \
    const int fr   = lane & 15; \
    const int fq   = lane >> 4; \
    const int lro2 = (lane >> 2) * 32 + (((lane & 3) ^ ((lane >> 3) & 3)) * 8); \
    const int fqx2 = (fq ^ ((fr >> 1) & 3)) * 8; \
    const int wrA  = wv * 32; \
    const int wrB  = wv * 16;

#define G_STAGE_A(buf_, t_) { \
    u16* d_ = (buf_); \
    const long long ao_ = abase + (long long)(t_) * astep; \
    gld16(Ahp + ao_ + (long long)wrA * 32 + lro2, d_ + wrA * 32); \
    gld16(Ahp + ao_ + (long long)(wrA + 16) * 32 + lro2, d_ + (wrA + 16) * 32); \
    gld16(Alp + ao_ + (long long)wrA * 32 + lro2, d_ + 8192 + wrA * 32); \
    gld16(Alp + ao_ + (long long)(wrA + 16) * 32 + lro2, d_ + 8192 + (wrA + 16) * 32); }

#define G_STAGE_B(buf_, t_) { \
    u16* d_ = (buf_); \
    const long long bo_ = bbase + (long long)(t_) * 32768; \
    gld16(Bhp + bo_ + (long long)wrB * 32 + lro2, d_ + 16384 + wrB * 32); \
    gld16(Blp + bo_ + (long long)wrB * 32 + lro2, d_ + 20480 + wrB * 32); }

#define G_RD_A(AH_, AL_, bp_) \
    _Pragma("unroll") \
    for (int i_ = 0; i_ < 4; i_++) { \
        const int off_ = (wm * 64 + i_ * 16 + fr) * 32 + fqx2; \
        AH_[i_] = *(const bf16x8*)((bp_) + off_); \
        AL_[i_] = *(const bf16x8*)((bp_) + 8192 + off_); }

#define G_RD_B(bp_, JB) \
    _Pragma("unroll") \
    for (int j_ = 0; j_ < 2; j_++) { \
        const int off_ = (wn * 64 + ((JB) + j_) * 16 + fr) * 32 + fqx2; \
        bh[(JB) + j_] = *(const bf16x8*)((bp_) + 16384 + off_); \
        bl[(JB) + j_] = *(const bf16x8*)((bp_) + 20480 + off_); }

// one K-tile; AH_/AL_ = current A frags, NAH_/NAL_ = prefetch target set
#define G_TILE(t_, AH_, AL_, NAH_, NAL_) { \
    const u16* bp = smem + ((t_) % 3) * 24576; \
    u16* nb2 = smem + (((t_) + 2) % 3) * 24576; \
    const u16* np = smem + (((t_) + 1) % 3) * 24576; \
    const bool s_ = (t_) + 2 < KT; \
    const bool p_ = (t_) + 1 < KT; \
    G_RD_B(bp, 2) \
    if (s_) { G_STAGE_A(nb2, (t_) + 2); G_STAGE_B(nb2, (t_) + 2); } \
    SCHED0; \
    MFMA_Q24(AH_, AL_, 0, 0) \
    asm volatile("s_waitcnt lgkmcnt(0)" ::: "memory"); \
    if (s_) { asm volatile("s_waitcnt vmcnt(6)" ::: "memory"); } \
    else    { asm volatile("s_waitcnt vmcnt(0)" ::: "memory"); } \
    __builtin_amdgcn_s_barrier(); \
    SCHED0; \
    if (p_) { G_RD_A(NAH_, NAL_, np) G_RD_B(np, 0) } \
    SCHED0; \
    MFMA_Q24(AH_, AL_, 0, 2) \
    SCHED0; \
}

template <int RELU, int OUTP>
__global__ __launch_bounds__(512, 2) void gemm_fast(
    const u16* __restrict__ Ahp, const u16* __restrict__ Alp, int MA, int moff,
    const u16* __restrict__ Bhp, const u16* __restrict__ Blp,
    const float* __restrict__ bias,
    float* __restrict__ Cf,
    u16* __restrict__ Chp, u16* __restrict__ Clp, int MC,
    int K)
{
    __shared__ alignas(16) u16 smem[3 * 24576];
    G_GEOM

    f32x4 acc[4][4];
#pragma unroll
    for (int i = 0; i < 4; i++)
#pragma unroll
        for (int j = 0; j < 4; j++) acc[i][j] = 0;

    const int KT = K >> 5;
    const long long astep = (long long)MA * 32;
    const long long abase = ((long long)moff + m0) * 32;
    const long long bbase = (long long)n0 * 32;

    bf16x8 ahA[4], alA[4], ahB[4], alB[4], bh[4], bl[4];

    G_STAGE_A(smem, 0); G_STAGE_B(smem, 0);
    G_STAGE_A(smem + 24576, 1); G_STAGE_B(smem + 24576, 1);
    asm volatile("s_waitcnt vmcnt(6)" ::: "memory");
    __builtin_amdgcn_s_barrier();
    SCHED0;
    G_RD_A(ahA, alA, smem)
    G_RD_B(smem, 0)

    for (int t = 0; t < KT; t += 2) {
        G_TILE(t,     ahA, alA, ahB, alB)
        G_TILE(t + 1, ahB, alB, ahA, alA)
    }

#pragma unroll
    for (int j = 0; j < 4; j++) {
        const int n = n0 + wn * 64 + j * 16 + fr;
        const float bb = bias[n];
#pragma unroll
        for (int i = 0; i < 4; i++) {
#pragma unroll
            for (int r = 0; r < 4; r++) {
                const int m = m0 + wm * 64 + i * 16 + fq * 4 + r;
                float v = acc[i][j][r] + bb;
                if (RELU) v = fmaxf(v, 0.0f);
                if (OUTP) {
                    u16 h, l;
                    split1(v, h, l);
                    const long long d = ((long long)(n >> 5) * MC + moff + m) * 32 + (n & 31);
                    Chp[d] = h;
                    Clp[d] = l;
                } else {
                    Cf[(long long)m * 1024 + n] = v;
                }
            }
        }
    }
}

// ===========================================================================
// Heads: 256x256 tile per head, 8 waves (2M x 4N, per-wave 128x64).
// LDS ring of 2 x 64 KiB; read-ahead pipeline, ONE barrier per K-tile.
// Epilogue: exact fp32 score part-dot (unchanged numerics), then headsb
// written via LDS transpose -> fully-coalesced 512B row stores (kills the
// RMW over-fetch + write amplification of scattered 2B stores).
// Grid (4, BC/256, 8).
// ===========================================================================
#define H_STAGE_A(buf_, t_) { \
    u16* d_ = (buf_); \
    const long long ao_ = abase + (long long)(t_) * astep; \
    gld16(Ahp + ao_ + (long long)wrA * 32 + lro2, d_ + wrA * 32); \
    gld16(Ahp + ao_ + (long long)(wrA + 16) * 32 + lro2, d_ + (wrA + 16) * 32); \
    gld16(Alp + ao_ + (long long)wrA * 32 + lro2, d_ + 8192 + wrA * 32); \
    gld16(Alp + ao_ + (long long)(wrA + 16) * 32 + lro2, d_ + 8192 + (wrA + 16) * 32); }

#define H_STAGE_B(buf_, t_) { \
    u16* d_ = (buf_); \
    const long long bo_ = bbase + (long long)(t_) * 32768; \
    gld16(Bhp + bo_ + (long long)wrA * 32 + lro2, d_ + 16384 + wrA * 32); \
    gld16(Bhp + bo_ + (long long)(wrA + 16) * 32 + lro2, d_ + 16384 + (wrA + 16) * 32); \
    gld16(Blp + bo_ + (long long)wrA * 32 + lro2, d_ + 24576 + wrA * 32); \
    gld16(Blp + bo_ + (long long)(wrA + 16) * 32 + lro2, d_ + 24576 + (wrA + 16) * 32); }

#define H_RD_A0(bp_) \
    _Pragma("unroll") \
    for (int i_ = 0; i_ < 4; i_++) { \
        const int off_ = (wm * 128 + i_ * 16 + fr) * 32 + fqx2; \
        ah0[i_] = *(const bf16x8*)((bp_) + off_); \
        al0[i_] = *(const bf16x8*)((bp_) + 8192 + off_); }

#define H_RD_A1(bp_) \
    _Pragma("unroll") \
    for (int i_ = 0; i_ < 4; i_++) { \
        const int off_ = (wm * 128 + 64 + i_ * 16 + fr) * 32 + fqx2; \
        ah1[i_] = *(const bf16x8*)((bp_) + off_); \
        al1[i_] = *(const bf16x8*)((bp_) + 8192 + off_); }

#define H_RD_B01(bp_) \
    _Pragma("unroll") \
    for (int j_ = 0; j_ < 2; j_++) { \
        const int off_ = (wn * 64 + j_ * 16 + fr) * 32 + fqx2; \
        bh[j_] = *(const bf16x8*)((bp_) + 16384 + off_); \
        bl[j_] = *(const bf16x8*)((bp_) + 24576 + off_); }

#define H_RD_B23(bp_) \
    _Pragma("unroll") \
    for (int j_ = 0; j_ < 2; j_++) { \
        const int off_ = (wn * 64 + (2 + j_) * 16 + fr) * 32 + fqx2; \
        bh[2 + j_] = *(const bf16x8*)((bp_) + 16384 + off_); \
        bl[2 + j_] = *(const bf16x8*)((bp_) + 24576 + off_); }

__global__ __launch_bounds__(512, 2) void heads_kernel(
    const u16* __restrict__ Ahp, const u16* __restrict__ Alp, int MA, int moff,
    const u16* __restrict__ Whp, const u16* __restrict__ Wlp,
    const float* __restrict__ b_heads,
    const float* __restrict__ decH,      // chunk-local [BC][1024]
    __half* __restrict__ headsb,         // [BC][8][1024]
    float* __restrict__ scoresp)         // [32][BC]
{
    __shared__ alignas(16) u16 smem[2 * 32768];
    __shared__ float scred[4][256];
    const int tid  = threadIdx.x;
    const int lane = tid & 63;
    const int wv   = tid >> 6;       // 0..7
    const int wm   = wv >> 2;        // 0..1 (128-row half)
    const int wn   = wv & 3;         // 0..3 (64-col quarter)
    const int fr   = lane & 15;
    const int fq   = lane >> 4;
    const int m0   = blockIdx.y * 256;
    const int n0   = blockIdx.x * 256;
    const int lro2 = (lane >> 2) * 32 + (((lane & 3) ^ ((lane >> 3) & 3)) * 8);
    const int fqx2 = (fq ^ ((fr >> 1) & 3)) * 8;
    const int wrA  = wv * 32;
    const int h = blockIdx.z;
    const u16* Bhp = Whp + (long long)h * 1048576;
    const u16* Blp = Wlp + (long long)h * 1048576;
    const float* bias = b_heads + h * 1024;

    f32x4 acc[8][4];
#pragma unroll
    for (int i = 0; i < 8; i++)
#pragma unroll
        for (int j = 0; j < 4; j++) acc[i][j] = 0;

    const long long astep = (long long)MA * 32;
    const long long abase = ((long long)moff + m0) * 32;
    const long long bbase = (long long)n0 * 32;

    bf16x8 ah0[4], al0[4], ah1[4], al1[4], bh[4], bl[4];

    H_STAGE_A(smem, 0);
    H_STAGE_B(smem, 0);
    asm volatile("s_waitcnt vmcnt(0)" ::: "memory");
    __builtin_amdgcn_s_barrier();
    SCHED0;
    H_RD_A0(smem)
    H_RD_B01(smem)

    for (int t = 0; t < 32; t++) {
        const u16* bp = smem + (t & 1) * 32768;
        u16* nb = smem + ((t + 1) & 1) * 32768;
        const bool more = t < 31;
        // ph1: Q(0..3, 0..1) uses ah0,b01; read B23(this tile); stage A(t+1)
        H_RD_B23(bp)
        if (more) H_STAGE_A(nb, t + 1);
        SCHED0;
        MFMA_Q24(ah0, al0, 0, 0)
        SCHED0;
        // ph2: Q(0..3, 2..3) uses ah0,b23; read A1(this tile); stage B(t+1)
        H_RD_A1(bp)
        if (more) H_STAGE_B(nb, t + 1);
        SCHED0;
        MFMA_Q24(ah0, al0, 0, 2)
        SCHED0;
        // ph3: Q(4..7, 0..1) uses ah1,b01; then tile checkpoint
        MFMA_Q24(ah1, al1, 4, 0)
        asm volatile("s_waitcnt lgkmcnt(0)" ::: "memory");
        asm volatile("s_waitcnt vmcnt(0)" ::: "memory");
        __builtin_amdgcn_s_barrier();
        SCHED0;
        // ph4: Q(4..7, 2..3) uses ah1,b23; prefetch next tile's A0,B01
        if (more) { H_RD_A0(nb) H_RD_B01(nb) }
        SCHED0;
        MFMA_Q24(ah1, al1, 4, 2)
        SCHED0;
    }

    // ---- score partials: exact fp32 path (unchanged numerics) -------------
    float part[8][4];
#pragma unroll
    for (int i = 0; i < 8; i++)
#pragma unroll
        for (int r = 0; r < 4; r++) part[i][r] = 0.0f;

#pragma unroll
    for (int j = 0; j < 4; j++) {
        const int n = n0 + wn * 64 + j * 16 + fr;
        const float bb = bias[n];
#pragma unroll
        for (int i = 0; i < 8; i++) {
#pragma unroll
            for (int r = 0; r < 4; r++) {
                const int b_loc = m0 + wm * 128 + i * 16 + fq * 4 + r;
                const float v = fmaxf(acc[i][j][r] + bb, 0.0f);
                part[i][r] = fmaf(v, decH[(long long)b_loc * 1024 + n], part[i][r]);
            }
        }
    }

    // ---- headsb via LDS transpose: two 128-row passes ---------------------
    // write: row-local pitch 260 halves; lanes hit 32 distinct bank-slots
    // (<=2-way same-dword merge).  read+store: one wave streams one row of
    // 256 halves = 512B fully coalesced global store.
#pragma unroll
    for (int pss = 0; pss < 2; pss++) {
        __syncthreads();
        if (wm == pss) {
#pragma unroll
            for (int j = 0; j < 4; j++) {
                const int n = n0 + wn * 64 + j * 16 + fr;
                const float bb = bias[n];
#pragma unroll
                for (int i = 0; i < 8; i++) {
#pragma unroll
                    for (int r = 0; r < 4; r++) {
                        const float v = fmaxf(acc[i][j][r] + bb, 0.0f);
                        smem[(i * 16 + fq * 4 + r) * 260 + wn * 64 + j * 16 + fr] =
                            __half_as_ushort(__float2half(v));
                    }
                }
            }
        }
        __syncthreads();
#pragma unroll
        for (int it = 0; it < 16; it++) {
            const int row = it * 8 + wv;
            const uint2 d = *(const uint2*)(smem + row * 260 + lane * 4);
            __half* hb = headsb + ((long long)(m0 + pss * 128 + row) * HEADS + h) * 1024
                       + n0 + lane * 4;
            *(uint2*)hb = d;
        }
    }

    // ---- score reduction --------------------------------------------------
#pragma unroll
    for (int off = 1; off < 16; off <<= 1)
#pragma unroll
        for (int i = 0; i < 8; i++)
#pragma unroll
            for (int r = 0; r < 4; r++)
                part[i][r] += __shfl_xor(part[i][r], off, 64);

    if (fr == 0) {
#pragma unroll
        for (int i = 0; i < 8; i++)
#pragma unroll
            for (int r = 0; r < 4; r++)
                scred[wn][wm * 128 + i * 16 + fq * 4 + r] = part[i][r];
    }
    __syncthreads();
    if (tid < 256) {
        const float sv = scred[0][tid] + scred[1][tid] + scred[2][tid] + scred[3][tid];
        scoresp[(long long)(h * 4 + blockIdx.x) * BC + m0 + tid] = sv;
    }
}

// ===========================================================================
// GEMM (convert path, enc/dec): A fp32 (2-region concat), split in-kernel
// via LDS; B async from planes.  Output: hi/lo planes.
// ===========================================================================
template <int RELU>
__global__ __launch_bounds__(256) void gemm_cvt(
    const float* __restrict__ src1, int lda1, int kofs1,
    const float* __restrict__ src2, int lda2, int ksplit,
    const u16* __restrict__ Bhp, const u16* __restrict__ Blp,
    const float* __restrict__ bias,
    u16* __restrict__ Chp, u16* __restrict__ Clp, int MC,
    int K)
{
    __shared__ alignas(16) u16 Ah[4096], Al[4096], Bh[4096], Bl[4096];
    const int tid  = threadIdx.x;
    const int lane = tid & 63;
    const int wv   = tid >> 6;
    const int wm   = wv >> 1, wn = wv & 1;
    const int fr   = lane & 15;
    const int fq   = lane >> 4;
    const int m0   = blockIdx.y * 128;
    const int n0   = blockIdx.x * 128;
    const int fqx  = (fq ^ (fr & 3)) * 8;
    const int lro  = (lane >> 2) * 32 + (((lane & 3) ^ ((lane >> 2) & 3)) * 8);
    const int br0  = wv * 16;
    const int br1  = 64 + wv * 16;
    const int ar   = tid >> 3;           // 0..31
    const int akq  = tid & 7;            // float4 group 0..7
    const int awoff = (((akq >> 1) ^ (ar & 3)) * 8) + (akq & 1) * 4;

    f32x4 acc[4][4];
#pragma unroll
    for (int i = 0; i < 4; i++)
#pragma unroll
        for (int j = 0; j < 4; j++) acc[i][j] = 0;

    const int KT = K >> 5;
    for (int kt = 0; kt < KT; kt++) {
        const int k0 = kt * 32;
        const float* srcp; int ldk, kc;
        if (k0 < ksplit) { srcp = src1; ldk = lda1; kc = k0 + kofs1; }
        else             { srcp = src2; ldk = lda2; kc = k0 - ksplit; }

        const u16* Bg  = Bhp + ((long long)kt * 1024 + n0) * 32;
        const u16* Bg2 = Blp + ((long long)kt * 1024 + n0) * 32;
        gld16(Bg  + br0 * 32 + lro, &Bh[br0 * 32]);
        gld16(Bg  + br1 * 32 + lro, &Bh[br1 * 32]);
        gld16(Bg2 + br0 * 32 + lro, &Bl[br0 * 32]);
        gld16(Bg2 + br1 * 32 + lro, &Bl[br1 * 32]);

#pragma unroll
        for (int it = 0; it < 4; it++) {
            const int row = ar + it * 32;
            const float4 v = *(const float4*)(srcp + (long long)(m0 + row) * ldk + kc + akq * 4);
            uint2 hi, lo;
            splitA4(v, hi, lo);
            *(uint2*)&Ah[row * 32 + awoff] = hi;
            *(uint2*)&Al[row * 32 + awoff] = lo;
        }
        __syncthreads();

        bf16x8 ah[4], al[4], bh[4], bl[4];
#pragma unroll
        for (int i = 0; i < 4; i++) {
            const int off = (wm * 64 + i * 16 + fr) * 32 + fqx;
            ah[i] = *(const bf16x8*)&Ah[off];
            al[i] = *(const bf16x8*)&Al[off];
        }
#pragma unroll
        for (int j = 0; j < 4; j++) {
            const int off = (wn * 64 + j * 16 + fr) * 32 + fqx;
            bh[j] = *(const bf16x8*)&Bh[off];
            bl[j] = *(const bf16x8*)&Bl[off];
        }
#pragma unroll
        for (int i = 0; i < 4; i++)
#pragma unroll
            for (int j = 0; j < 4; j++) {
                acc[i][j] = __builtin_amdgcn_mfma_f32_16x16x32_bf16(ah[i], bh[j], acc[i][j], 0, 0, 0);
                acc[i][j] = __builtin_amdgcn_mfma_f32_16x16x32_bf16(ah[i], bl[j], acc[i][j], 0, 0, 0);
                acc[i][j] = __builtin_amdgcn_mfma_f32_16x16x32_bf16(al[i], bh[j], acc[i][j], 0, 0, 0);
            }
        __syncthreads();
    }

#pragma unroll
    for (int j = 0; j < 4; j++) {
        const int n = n0 + wn * 64 + j * 16 + fr;
        const float bb = bias[n];
#pragma unroll
        for (int i = 0; i < 4; i++) {
#pragma unroll
            for (int r = 0; r < 4; r++) {
                const int m = m0 + wm * 64 + i * 16 + fq * 4 + r;
                float v = acc[i][j][r] + bb;
                if (RELU) v = fmaxf(v, 0.0f);
                u16 h, l;
                split1(v, h, l);
                const long long d = ((long long)(n >> 5) * MC + m) * 32 + (n & 31);
                Chp[d] = h;
                Clp[d] = l;
            }
        }
    }
}

// ---------------------------------------------------------------------------
// context (+fused softmax): per row b, softmax over heads from scoresp
// ([32][BC]: 4 n-tiles per head), then ctx[b][d] = sum_h attn[h]*heads;
// writes hi/lo planes.
// ---------------------------------------------------------------------------
__global__ __launch_bounds__(256) void context_kernel(
    const __half* __restrict__ headsb, const float* __restrict__ scoresp,
    u16* __restrict__ ctx_hi, u16* __restrict__ ctx_lo, int MC, int row0)
{
    __shared__ float sc_s[32];
    __shared__ float attn_s[HEADS];
    const int b = blockIdx.x;
    const int tid = threadIdx.x;
    if (tid < 32) sc_s[tid] = scoresp[(long long)tid * BC + b];
    __syncthreads();
    if (tid == 0) {
        float sc[HEADS];
#pragma unroll
        for (int h = 0; h < HEADS; h++) {
            float s = 0.0f;
#pragma unroll
            for (int nt = 0; nt < 4; nt++) s += sc_s[h * 4 + nt];
            sc[h] = s;
        }
        float mx = sc[0];
#pragma unroll
        for (int h = 1; h < HEADS; h++) mx = fmaxf(mx, sc[h]);
        float e[HEADS], sum = 0.0f;
#pragma unroll
        for (int h = 0; h < HEADS; h++) { e[h] = __expf(sc[h] - mx); sum += e[h]; }
        const float inv = 1.0f / sum;
#pragma unroll
        for (int h = 0; h < HEADS; h++) attn_s[h] = e[h] * inv;
    }
    __syncthreads();

    const int d = tid * 4;
    float w[HEADS];
#pragma unroll
    for (int h = 0; h < HEADS; h++) w[h] = attn_s[h];
    float4 acc = make_float4(0.f, 0.f, 0.f, 0.f);
#pragma unroll
    for (int h = 0; h < HEADS; h++) {
        const __half2* hp = (const __half2*)(headsb + ((long long)b * HEADS + h) * 1024 + d);
        const float2 f0 = __half22float2(hp[0]);
        const float2 f1 = __half22float2(hp[1]);
        acc.x = fmaf(w[h], f0.x, acc.x);
        acc.y = fmaf(w[h], f0.y, acc.y);
        acc.z = fmaf(w[h], f1.x, acc.z);
        acc.w = fmaf(w[h], f1.y, acc.w);
    }
    uint2 hi, lo;
    splitA4(acc, hi, lo);
    const long long off = ((long long)(d >> 5) * MC + row0 + b) * 32 + (d & 31);
    *(uint2*)(ctx_hi + off) = hi;
    *(uint2*)(ctx_lo + off) = lo;
}

// ---------------------------------------------------------------------------
// fc2: q[b] = sum_d x[b,d]*W2[d] + b2[0]
// ---------------------------------------------------------------------------
__global__ __launch_bounds__(256) void fc2_kernel(
    const float* __restrict__ x, const float* __restrict__ W2,
    const float* __restrict__ b2, float* __restrict__ q)
{
    const int b   = blockIdx.x;
    const int tid = threadIdx.x;
    __shared__ float red[4];

    const float4 xv = *(const float4*)(x + (long long)b * 1024 + tid * 4);
    const float4 wv = *(const float4*)(W2 + tid * 4);
    float p = xv.x * wv.x + xv.y * wv.y + xv.z * wv.z + xv.w * wv.w;
#pragma unroll
    for (int off = 32; off > 0; off >>= 1) p += __shfl_down(p, off, 64);
    if ((tid & 63) == 0) red[tid >> 6] = p;
    __syncthreads();
    if (tid == 0) q[b] = red[0] + red[1] + red[2] + red[3] + b2[0];
}

// ---------------------------------------------------------------------------
extern "C" void kernel_launch(void* const* d_in, const int* in_sizes, int n_in,
                              void* d_out, int out_size, void* d_ws, size_t ws_size,
                              hipStream_t stream)
{
    const float* s        = (const float*)d_in[0];
    const float* a        = (const float*)d_in[1];
    const float* W_enc_in = (const float*)d_in[2];
    const float* b_enc_in = (const float*)d_in[3];
    const float* W_dec_in = (const float*)d_in[4];
    const float* b_dec_in = (const float*)d_in[5];
    const float* W_eh     = (const float*)d_in[6];
    const float* b_eh     = (const float*)d_in[7];
    const float* W_heads  = (const float*)d_in[8];
    const float* b_heads  = (const float*)d_in[9];
    const float* W_dh     = (const float*)d_in[10];
    const float* b_dh     = (const float*)d_in[11];
    const float* W1       = (const float*)d_in[12];
    const float* b1       = (const float*)d_in[13];
    const float* W2       = (const float*)d_in[14];
    const float* b2       = (const float*)d_in[15];
    float* q_out = (float*)d_out;

    // ---- weight plane layout (shorts) -------------------------------------
    u16* P = (u16*)d_ws;
    u16* enc_hi = P; P += 557056;      // 544*1024
    u16* enc_lo = P; P += 557056;
    u16* dec_hi = P; P += 98304;       // 96*1024
    u16* dec_lo = P; P += 98304;
    u16* eh_hi  = P; P += 1048576;
    u16* eh_lo  = P; P += 1048576;
    u16* dh_hi  = P; P += 1048576;
    u16* dh_lo  = P; P += 1048576;
    u16* w1_hi  = P; P += 1048576;
    u16* w1_lo  = P; P += 1048576;
    u16* wh_hi  = P; P += 8388608;     // 8*1024*1024
    u16* wh_lo  = P; P += 8388608;
    char* act = (char*)P;              // 48,758,784 bytes consumed

    const dim3 blk(256);
    const dim3 blk512(512);

    // ---- weight conversions: ONE launch -----------------------------------
    WSplitArgs wa;
    wa.src[0] = W_eh;    wa.hi[0] = eh_hi;  wa.lo[0] = eh_lo;
    wa.src[1] = W_dh;    wa.hi[1] = dh_hi;  wa.lo[1] = dh_lo;
    wa.src[2] = W1;      wa.hi[2] = w1_hi;  wa.lo[2] = w1_lo;
    wa.src[3] = W_heads; wa.hi[3] = wh_hi;  wa.lo[3] = wh_lo;
    wa.src[4] = W_enc_in; wa.hi[4] = enc_hi; wa.lo[4] = enc_lo;
    wa.src[5] = W_dec_in; wa.hi[5] = dec_hi; wa.lo[5] = dec_lo;
    split_weight_all<<<dim3(32, 8, 13), blk, 0, stream>>>(wa);

    const bool high = (ws_size >= 150011904ULL);

    if (high) {
        u16*    bufA_hi = (u16*)act;
        u16*    bufA_lo = bufA_hi + 8388608;
        __half* headsb  = (__half*)act;
        u16*    encH_hi = (u16*)(act + 33554432);
        u16*    encH_lo = encH_hi + 8388608;
        float*  decH    = (float*)(act + 2LL * 33554432);
        float*  scoresp = (float*)(act + 3LL * 33554432);

        const dim3 ggc(8, 64, 1);      // cvt kernels: 128-row tiles
        const dim3 ggf(8, 32, 1);      // gemm_fast: 256x128 tiles
        gemm_cvt<0><<<ggc, blk, 0, stream>>>(s, 512, 0, a, 128, 512,
            enc_hi, enc_lo, b_enc_in, bufA_hi, bufA_lo, 8192, 544);
        gemm_fast<1, 1><<<ggf, blk512, 0, stream>>>(bufA_hi, bufA_lo, 8192, 0,
            eh_hi, eh_lo, b_eh, nullptr, encH_hi, encH_lo, 8192, 1024);
        gemm_cvt<0><<<ggc, blk, 0, stream>>>(a, 128, 32, a, 128, 1 << 28,
            dec_hi, dec_lo, b_dec_in, bufA_hi, bufA_lo, 8192, 96);
        gemm_fast<1, 0><<<ggf, blk512, 0, stream>>>(bufA_hi, bufA_lo, 8192, 0,
            dh_hi, dh_lo, b_dh, decH, nullptr, nullptr, 0, 1024);

        for (int c = 0; c < BATCH / BC; c++) {
            heads_kernel<<<dim3(4, BC / 256, 8), blk512, 0, stream>>>(
                encH_hi, encH_lo, 8192, c * BC, wh_hi, wh_lo, b_heads,
                decH + (long long)c * BC * 1024, headsb, scoresp);
            context_kernel<<<dim3(BC), blk, 0, stream>>>(
                headsb, scoresp, encH_hi, encH_lo, 8192, c * BC);
        }
        gemm_fast<1, 0><<<ggf, blk512, 0, stream>>>(encH_hi, encH_lo, 8192, 0,
            w1_hi, w1_lo, b1, decH, nullptr, nullptr, 0, 1024);
        fc2_kernel<<<dim3(BATCH), blk, 0, stream>>>(decH, W2, b2, q_out);
    } else {
        __half* headsb  = (__half*)act;
        u16*    bufA_hi = (u16*)act;
        u16*    bufA_lo = bufA_hi + 2097152;
        u16*    encH_hi = (u16*)(act + 33554432);
        u16*    encH_lo = encH_hi + 2097152;
        float*  decH    = (float*)(act + 33554432 + 8388608);
        float*  scoresp = (float*)(act + 33554432 + 2LL * 8388608);

        const dim3 ggc(8, BC / 128, 1);
        const dim3 ggf(8, BC / 256, 1);
        for (int c = 0; c < BATCH / BC; c++) {
            const float* sC = s + (long long)c * BC * 512;
            const float* aC = a + (long long)c * BC * 128;
            gemm_cvt<0><<<ggc, blk, 0, stream>>>(sC, 512, 0, aC, 128, 512,
                enc_hi, enc_lo, b_enc_in, bufA_hi, bufA_lo, BC, 544);
            gemm_fast<1, 1><<<ggf, blk512, 0, stream>>>(bufA_hi, bufA_lo, BC, 0,
                eh_hi, eh_lo, b_eh, nullptr, encH_hi, encH_lo, BC, 1024);
            gemm_cvt<0><<<ggc, blk, 0, stream>>>(aC, 128, 32, aC, 128, 1 << 28,
                dec_hi, dec_lo, b_dec_in, bufA_hi, bufA_lo, BC, 96);
            gemm_fast<1, 0><<<ggf, blk512, 0, stream>>>(bufA_hi, bufA_lo, BC, 0,
                dh_hi, dh_lo, b_dh, decH, nullptr, nullptr, 0, 1024);
            heads_kernel<<<dim3(4, BC / 256, 8), blk512, 0, stream>>>(
                encH_hi, encH_lo, BC, 0, wh_hi, wh_lo, b_heads,
                decH, headsb, scoresp);
            context_kernel<<<dim3(BC), blk, 0, stream>>>(
                headsb, scoresp, encH_hi, encH_lo, BC, 0);
            gemm_fast<1, 0><<<ggf, blk512, 0, stream>>>(encH_hi, encH_lo, BC, 0,
                w1_hi, w1_lo, b1, decH, nullptr, nullptr, 0, 1024);
            fc2_kernel<<<dim3(BC), blk, 0, stream>>>(decH, W2, b2, q_out + (long long)c * BC);
        }
    }
}

// Round 7
// 670.873 us; speedup vs baseline: 1.2051x; 1.0388x over previous
//
#include <hip/hip_runtime.h>
#include <hip/hip_bf16.h>
#include <hip/hip_fp16.h>

#define BATCH   8192
#define HID     1024
#define HEADS   8
#define BC      2048

typedef unsigned int  u32;
typedef unsigned short u16;
typedef __attribute__((ext_vector_type(8))) short bf16x8;
typedef __attribute__((ext_vector_type(4))) float f32x4;

// ---------------------------------------------------------------------------
// hi/lo split helpers (truncation both; x = hi + lo + O(2^-16 |x|))
// ---------------------------------------------------------------------------
__device__ __forceinline__ u32 pack_hi2(u32 u0, u32 u1) {
    return (u0 >> 16) | (u1 & 0xFFFF0000u);
}
__device__ __forceinline__ void split1(float x, u16& h, u16& l) {
    const u32 u = __float_as_uint(x);
    h = (u16)(u >> 16);
    const float r = x - __uint_as_float(u & 0xFFFF0000u);
    l = (u16)(__float_as_uint(r) >> 16);
}
__device__ __forceinline__ void splitA4(float4 v, uint2& hi, uint2& lo) {
    u32 u0 = __float_as_uint(v.x), u1 = __float_as_uint(v.y),
        u2 = __float_as_uint(v.z), u3 = __float_as_uint(v.w);
    float r0 = v.x - __uint_as_float(u0 & 0xFFFF0000u);
    float r1 = v.y - __uint_as_float(u1 & 0xFFFF0000u);
    float r2 = v.z - __uint_as_float(u2 & 0xFFFF0000u);
    float r3 = v.w - __uint_as_float(u3 & 0xFFFF0000u);
    hi.x = pack_hi2(u0, u1);
    hi.y = pack_hi2(u2, u3);
    lo.x = pack_hi2(__float_as_uint(r0), __float_as_uint(r1));
    lo.y = pack_hi2(__float_as_uint(r2), __float_as_uint(r3));
}

// async global->LDS, 16 B per lane; lds base must be wave-uniform
__device__ __forceinline__ void gld16(const u16* g, u16* l) {
    __builtin_amdgcn_global_load_lds(
        (const __attribute__((address_space(1))) u32*)g,
        (__attribute__((address_space(3))) u32*)l, 16, 0, 0);
}

#define SCHED0 __builtin_amdgcn_sched_barrier(0)

// ---------------------------------------------------------------------------
// Combined weight conversion (ONE launch): 13 z-slices ->
//  z=0 eh, z=1 dh, z=2 w1, z=3..10 heads h, z=11 enc, z=12 dec
// W fp32 [K][1024] -> hi/lo planes, k-tiled transposed  Wt[kt][n][32].
// ---------------------------------------------------------------------------
struct WSplitArgs {
    const float* src[6];
    u16* hi[6];
    u16* lo[6];
};

__global__ __launch_bounds__(256) void split_weight_all(WSplitArgs args)
{
    const int z = blockIdx.z;
    int which, zz = 0;
    if (z < 3)       { which = z; }
    else if (z < 11) { which = 3; zz = z - 3; }
    else             { which = z - 7; }          // 4 = enc, 5 = dec
    const int KT = (which == 4) ? 17 : (which == 5 ? 3 : 32);
    const int kt = blockIdx.x;
    if (kt >= KT) return;
    const int K = KT * 32;
    const long long zoff = (long long)zz * K * 1024;
    const float* W  = args.src[which] + zoff;
    u16* hi = args.hi[which] + zoff;
    u16* lo = args.lo[which] + zoff;

    const int n0  = blockIdx.y * 128;
    const int tid = threadIdx.x;
    const int k   = tid >> 3;            // 0..31
    const int ng  = (tid & 7) * 16;      // 0,16,...,112
    const float* src = W + (long long)(kt * 32 + k) * 1024 + n0 + ng;
    u16* dh = hi + ((long long)kt * 1024 + n0) * 32 + k;
    u16* dl = lo + ((long long)kt * 1024 + n0) * 32 + k;
#pragma unroll
    for (int t = 0; t < 4; t++) {
        const float4 v = *(const float4*)(src + t * 4);
        u16 h0, l0, h1, l1, h2, l2, h3, l3;
        split1(v.x, h0, l0); split1(v.y, h1, l1);
        split1(v.z, h2, l2); split1(v.w, h3, l3);
        const int nb = (ng + t * 4) * 32;
        dh[nb]      = h0; dl[nb]      = l0;
        dh[nb + 32] = h1; dl[nb + 32] = l1;
        dh[nb + 64] = h2; dl[nb + 64] = l2;
        dh[nb + 96] = h3; dl[nb + 96] = l3;
    }
}

// ===========================================================================
// 24-MFMA quadrant cluster (8 hh, 8 hl, 8 lh), setprio-wrapped.
// Per-element order hh -> hl -> lh (bit-identical to previous rounds).
// ===========================================================================
#define MFMA_Q24(AH_, AL_, IB, JB) \
    __builtin_amdgcn_s_setprio(1); \
    _Pragma("unroll") \
    for (int i_ = 0; i_ < 4; i_++) \
        _Pragma("unroll") \
        for (int j_ = 0; j_ < 2; j_++) \
            acc[(IB) + i_][(JB) + j_] = __builtin_amdgcn_mfma_f32_16x16x32_bf16(AH_[i_], bh[(JB) + j_], acc[(IB) + i_][(JB) + j_], 0, 0, 0); \
    _Pragma("unroll") \
    for (int i_ = 0; i_ < 4; i_++) \
        _Pragma("unroll") \
        for (int j_ = 0; j_ < 2; j_++) \
            acc[(IB) + i_][(JB) + j_] = __builtin_amdgcn_mfma_f32_16x16x32_bf16(AH_[i_], bl[(JB) + j_], acc[(IB) + i_][(JB) + j_], 0, 0, 0); \
    _Pragma("unroll") \
    for (int i_ = 0; i_ < 4; i_++) \
        _Pragma("unroll") \
        for (int j_ = 0; j_ < 2; j_++) \
            acc[(IB) + i_][(JB) + j_] = __builtin_amdgcn_mfma_f32_16x16x32_bf16(AL_[i_], bh[(JB) + j_], acc[(IB) + i_][(JB) + j_], 0, 0, 0); \
    __builtin_amdgcn_s_setprio(0);

// ===========================================================================
// GEMM fast path: 256x128 tile, 8 waves (4M x 2N, per-wave 64x64).
// Ring of 3 x 48 KiB; read-ahead pipeline (frag ds_reads one phase early),
// ONE lgkmcnt(0)+vmcnt(6)+barrier per K-tile, K-loop unrolled x2 with
// alternating A register sets.
// OUTP: 0 = fp32 rows to Cf, 1 = hi/lo planes, 2 = fused fc2 (atomicAdd q).
// ===========================================================================
#define G_GEOM \
    const int tid  = threadIdx.x; \
    const int lane = tid & 63; \
    const int wv   = tid >> 6; \
    const int wm   = wv >> 1, wn = wv & 1; \
    const int m0   = blockIdx.y * 256; \
    const int n0   = blockIdx.x * 128; \
    const int fr   = lane & 15; \
    const int fq   = lane >> 4; \
    const int lro2 = (lane >> 2) * 32 + (((lane & 3) ^ ((lane >> 3) & 3)) * 8); \
    const int fqx2 = (fq ^ ((fr >> 1) & 3)) * 8; \
    const int wrA  = wv * 32; \
    const int wrB  = wv * 16;

#define G_STAGE_A(buf_, t_) { \
    u16* d_ = (buf_); \
    const long long ao_ = abase + (long long)(t_) * astep; \
    gld16(Ahp + ao_ + (long long)wrA * 32 + lro2, d_ + wrA * 32); \
    gld16(Ahp + ao_ + (long long)(wrA + 16) * 32 + lro2, d_ + (wrA + 16) * 32); \
    gld16(Alp + ao_ + (long long)wrA * 32 + lro2, d_ + 8192 + wrA * 32); \
    gld16(Alp + ao_ + (long long)(wrA + 16) * 32 + lro2, d_ + 8192 + (wrA + 16) * 32); }

#define G_STAGE_B(buf_, t_) { \
    u16* d_ = (buf_); \
    const long long bo_ = bbase + (long long)(t_) * 32768; \
    gld16(Bhp + bo_ + (long long)wrB * 32 + lro2, d_ + 16384 + wrB * 32); \
    gld16(Blp + bo_ + (long long)wrB * 32 + lro2, d_ + 20480 + wrB * 32); }

#define G_RD_A(AH_, AL_, bp_) \
    _Pragma("unroll") \
    for (int i_ = 0; i_ < 4; i_++) { \
        const int off_ = (wm * 64 + i_ * 16 + fr) * 32 + fqx2; \
        AH_[i_] = *(const bf16x8*)((bp_) + off_); \
        AL_[i_] = *(const bf16x8*)((bp_) + 8192 + off_); }

#define G_RD_B(bp_, JB) \
    _Pragma("unroll") \
    for (int j_ = 0; j_ < 2; j_++) { \
        const int off_ = (wn * 64 + ((JB) + j_) * 16 + fr) * 32 + fqx2; \
        bh[(JB) + j_] = *(const bf16x8*)((bp_) + 16384 + off_); \
        bl[(JB) + j_] = *(const bf16x8*)((bp_) + 20480 + off_); }

// one K-tile; AH_/AL_ = current A frags, NAH_/NAL_ = prefetch target set
#define G_TILE(t_, AH_, AL_, NAH_, NAL_) { \
    const u16* bp = smem + ((t_) % 3) * 24576; \
    u16* nb2 = smem + (((t_) + 2) % 3) * 24576; \
    const u16* np = smem + (((t_) + 1) % 3) * 24576; \
    const bool s_ = (t_) + 2 < KT; \
    const bool p_ = (t_) + 1 < KT; \
    G_RD_B(bp, 2) \
    if (s_) { G_STAGE_A(nb2, (t_) + 2); G_STAGE_B(nb2, (t_) + 2); } \
    SCHED0; \
    MFMA_Q24(AH_, AL_, 0, 0) \
    asm volatile("s_waitcnt lgkmcnt(0)" ::: "memory"); \
    if (s_) { asm volatile("s_waitcnt vmcnt(6)" ::: "memory"); } \
    else    { asm volatile("s_waitcnt vmcnt(0)" ::: "memory"); } \
    __builtin_amdgcn_s_barrier(); \
    SCHED0; \
    if (p_) { G_RD_A(NAH_, NAL_, np) G_RD_B(np, 0) } \
    SCHED0; \
    MFMA_Q24(AH_, AL_, 0, 2) \
    SCHED0; \
}

template <int RELU, int OUTP>
__global__ __launch_bounds__(512, 2) void gemm_fast(
    const u16* __restrict__ Ahp, const u16* __restrict__ Alp, int MA, int moff,
    const u16* __restrict__ Bhp, const u16* __restrict__ Blp,
    const float* __restrict__ bias,
    float* __restrict__ Cf,
    u16* __restrict__ Chp, u16* __restrict__ Clp, int MC,
    int K,
    const float* __restrict__ W2v, const float* __restrict__ b2v,
    float* __restrict__ qout)
{
    __shared__ alignas(16) u16 smem[3 * 24576];
    G_GEOM

    f32x4 acc[4][4];
#pragma unroll
    for (int i = 0; i < 4; i++)
#pragma unroll
        for (int j = 0; j < 4; j++) acc[i][j] = 0;

    const int KT = K >> 5;
    const long long astep = (long long)MA * 32;
    const long long abase = ((long long)moff + m0) * 32;
    const long long bbase = (long long)n0 * 32;

    bf16x8 ahA[4], alA[4], ahB[4], alB[4], bh[4], bl[4];

    G_STAGE_A(smem, 0); G_STAGE_B(smem, 0);
    G_STAGE_A(smem + 24576, 1); G_STAGE_B(smem + 24576, 1);
    asm volatile("s_waitcnt vmcnt(6)" ::: "memory");
    __builtin_amdgcn_s_barrier();
    SCHED0;
    G_RD_A(ahA, alA, smem)
    G_RD_B(smem, 0)

    for (int t = 0; t < KT; t += 2) {
        G_TILE(t,     ahA, alA, ahB, alB)
        G_TILE(t + 1, ahB, alB, ahA, alA)
    }

    if (OUTP == 2) {
        // fused fc2: q[m] += sum_n relu(x[m][n]) * W2[n]  (+ b2 once)
        float part[4][4];
#pragma unroll
        for (int i = 0; i < 4; i++)
#pragma unroll
            for (int r = 0; r < 4; r++) part[i][r] = 0.0f;
#pragma unroll
        for (int j = 0; j < 4; j++) {
            const int n = n0 + wn * 64 + j * 16 + fr;
            const float bb = bias[n];
            const float w2 = W2v[n];
#pragma unroll
            for (int i = 0; i < 4; i++) {
#pragma unroll
                for (int r = 0; r < 4; r++) {
                    const float v = fmaxf(acc[i][j][r] + bb, 0.0f);
                    part[i][r] = fmaf(v, w2, part[i][r]);
                }
            }
        }
#pragma unroll
        for (int off = 1; off < 16; off <<= 1)
#pragma unroll
            for (int i = 0; i < 4; i++)
#pragma unroll
                for (int r = 0; r < 4; r++)
                    part[i][r] += __shfl_xor(part[i][r], off, 64);
        if (fr == 0) {
            const float extra = (blockIdx.x == 0 && wn == 0) ? b2v[0] : 0.0f;
#pragma unroll
            for (int i = 0; i < 4; i++) {
#pragma unroll
                for (int r = 0; r < 4; r++) {
                    const int m = m0 + wm * 64 + i * 16 + fq * 4 + r;
                    atomicAdd(&qout[m], part[i][r] + extra);
                }
            }
        }
        return;
    }

#pragma unroll
    for (int j = 0; j < 4; j++) {
        const int n = n0 + wn * 64 + j * 16 + fr;
        const float bb = bias[n];
#pragma unroll
        for (int i = 0; i < 4; i++) {
#pragma unroll
            for (int r = 0; r < 4; r++) {
                const int m = m0 + wm * 64 + i * 16 + fq * 4 + r;
                float v = acc[i][j][r] + bb;
                if (RELU) v = fmaxf(v, 0.0f);
                if (OUTP == 1) {
                    u16 h, l;
                    split1(v, h, l);
                    const long long d = ((long long)(n >> 5) * MC + moff + m) * 32 + (n & 31);
                    Chp[d] = h;
                    Clp[d] = l;
                } else {
                    Cf[(long long)m * 1024 + n] = v;
                }
            }
        }
    }
}

// ===========================================================================
// Heads: 256x256 tile per head, 8 waves (2M x 4N, per-wave 128x64).
// LDS ring of 2 x 64 KiB; read-ahead pipeline, ONE barrier per K-tile.
// BOTH stages (A and B) issued in ph1 -> ~1860cy slack before the ph3-end
// vmcnt(0) drain (was ~930 for the B stage: right at HBM latency).
// Epilogue: exact fp32 score part-dot, headsb via LDS transpose (512B
// coalesced row stores).  Grid (4, BC/256, 8).
// ===========================================================================
#define H_STAGE_A(buf_, t_) { \
    u16* d_ = (buf_); \
    const long long ao_ = abase + (long long)(t_) * astep; \
    gld16(Ahp + ao_ + (long long)wrA * 32 + lro2, d_ + wrA * 32); \
    gld16(Ahp + ao_ + (long long)(wrA + 16) * 32 + lro2, d_ + (wrA + 16) * 32); \
    gld16(Alp + ao_ + (long long)wrA * 32 + lro2, d_ + 8192 + wrA * 32); \
    gld16(Alp + ao_ + (long long)(wrA + 16) * 32 + lro2, d_ + 8192 + (wrA + 16) * 32); }

#define H_STAGE_B(buf_, t_) { \
    u16* d_ = (buf_); \
    const long long bo_ = bbase + (long long)(t_) * 32768; \
    gld16(Bhp + bo_ + (long long)wrA * 32 + lro2, d_ + 16384 + wrA * 32); \
    gld16(Bhp + bo_ + (long long)(wrA + 16) * 32 + lro2, d_ + 16384 + (wrA + 16) * 32); \
    gld16(Blp + bo_ + (long long)wrA * 32 + lro2, d_ + 24576 + wrA * 32); \
    gld16(Blp + bo_ + (long long)(wrA + 16) * 32 + lro2, d_ + 24576 + (wrA + 16) * 32); }

#define H_RD_A0(bp_) \
    _Pragma("unroll") \
    for (int i_ = 0; i_ < 4; i_++) { \
        const int off_ = (wm * 128 + i_ * 16 + fr) * 32 + fqx2; \
        ah0[i_] = *(const bf16x8*)((bp_) + off_); \
        al0[i_] = *(const bf16x8*)((bp_) + 8192 + off_); }

#define H_RD_A1(bp_) \
    _Pragma("unroll") \
    for (int i_ = 0; i_ < 4; i_++) { \
        const int off_ = (wm * 128 + 64 + i_ * 16 + fr) * 32 + fqx2; \
        ah1[i_] = *(const bf16x8*)((bp_) + off_); \
        al1[i_] = *(const bf16x8*)((bp_) + 8192 + off_); }

#define H_RD_B01(bp_) \
    _Pragma("unroll") \
    for (int j_ = 0; j_ < 2; j_++) { \
        const int off_ = (wn * 64 + j_ * 16 + fr) * 32 + fqx2; \
        bh[j_] = *(const bf16x8*)((bp_) + 16384 + off_); \
        bl[j_] = *(const bf16x8*)((bp_) + 24576 + off_); }

#define H_RD_B23(bp_) \
    _Pragma("unroll") \
    for (int j_ = 0; j_ < 2; j_++) { \
        const int off_ = (wn * 64 + (2 + j_) * 16 + fr) * 32 + fqx2; \
        bh[2 + j_] = *(const bf16x8*)((bp_) + 16384 + off_); \
        bl[2 + j_] = *(const bf16x8*)((bp_) + 24576 + off_); }

__global__ __launch_bounds__(512, 2) void heads_kernel(
    const u16* __restrict__ Ahp, const u16* __restrict__ Alp, int MA, int moff,
    const u16* __restrict__ Whp, const u16* __restrict__ Wlp,
    const float* __restrict__ b_heads,
    const float* __restrict__ decH,      // chunk-local [BC][1024]
    __half* __restrict__ headsb,         // [BC][8][1024]
    float* __restrict__ scoresp)         // [32][BC]
{
    __shared__ alignas(16) u16 smem[2 * 32768];
    __shared__ float scred[4][256];
    const int tid  = threadIdx.x;
    const int lane = tid & 63;
    const int wv   = tid >> 6;       // 0..7
    const int wm   = wv >> 2;        // 0..1 (128-row half)
    const int wn   = wv & 3;         // 0..3 (64-col quarter)
    const int fr   = lane & 15;
    const int fq   = lane >> 4;
    const int m0   = blockIdx.y * 256;
    const int n0   = blockIdx.x * 256;
    const int lro2 = (lane >> 2) * 32 + (((lane & 3) ^ ((lane >> 3) & 3)) * 8);
    const int fqx2 = (fq ^ ((fr >> 1) & 3)) * 8;
    const int wrA  = wv * 32;
    const int h = blockIdx.z;
    const u16* Bhp = Whp + (long long)h * 1048576;
    const u16* Blp = Wlp + (long long)h * 1048576;
    const float* bias = b_heads + h * 1024;

    f32x4 acc[8][4];
#pragma unroll
    for (int i = 0; i < 8; i++)
#pragma unroll
        for (int j = 0; j < 4; j++) acc[i][j] = 0;

    const long long astep = (long long)MA * 32;
    const long long abase = ((long long)moff + m0) * 32;
    const long long bbase = (long long)n0 * 32;

    bf16x8 ah0[4], al0[4], ah1[4], al1[4], bh[4], bl[4];

    H_STAGE_A(smem, 0);
    H_STAGE_B(smem, 0);
    asm volatile("s_waitcnt vmcnt(0)" ::: "memory");
    __builtin_amdgcn_s_barrier();
    SCHED0;
    H_RD_A0(smem)
    H_RD_B01(smem)

    for (int t = 0; t < 32; t++) {
        const u16* bp = smem + (t & 1) * 32768;
        u16* nb = smem + ((t + 1) & 1) * 32768;
        const bool more = t < 31;
        // ph1: Q(0..3, 0..1) uses ah0,b01; read B23(this tile); stage A+B(t+1)
        H_RD_B23(bp)
        if (more) { H_STAGE_A(nb, t + 1); H_STAGE_B(nb, t + 1); }
        SCHED0;
        MFMA_Q24(ah0, al0, 0, 0)
        SCHED0;
        // ph2: Q(0..3, 2..3) uses ah0,b23; read A1(this tile)
        H_RD_A1(bp)
        SCHED0;
        MFMA_Q24(ah0, al0, 0, 2)
        SCHED0;
        // ph3: Q(4..7, 0..1) uses ah1,b01; then tile checkpoint
        MFMA_Q24(ah1, al1, 4, 0)
        asm volatile("s_waitcnt lgkmcnt(0)" ::: "memory");
        asm volatile("s_waitcnt vmcnt(0)" ::: "memory");
        __builtin_amdgcn_s_barrier();
        SCHED0;
        // ph4: Q(4..7, 2..3) uses ah1,b23; prefetch next tile's A0,B01
        if (more) { H_RD_A0(nb) H_RD_B01(nb) }
        SCHED0;
        MFMA_Q24(ah1, al1, 4, 2)
        SCHED0;
    }

    // ---- score partials: exact fp32 path (unchanged numerics) -------------
    float part[8][4];
#pragma unroll
    for (int i = 0; i < 8; i++)
#pragma unroll
        for (int r = 0; r < 4; r++) part[i][r] = 0.0f;

#pragma unroll
    for (int j = 0; j < 4; j++) {
        const int n = n0 + wn * 64 + j * 16 + fr;
        const float bb = bias[n];
#pragma unroll
        for (int i = 0; i < 8; i++) {
#pragma unroll
            for (int r = 0; r < 4; r++) {
                const int b_loc = m0 + wm * 128 + i * 16 + fq * 4 + r;
                const float v = fmaxf(acc[i][j][r] + bb, 0.0f);
                part[i][r] = fmaf(v, decH[(long long)b_loc * 1024 + n], part[i][r]);
            }
        }
    }

    // ---- headsb via LDS transpose: two 128-row passes ---------------------
#pragma unroll
    for (int pss = 0; pss < 2; pss++) {
        __syncthreads();
        if (wm == pss) {
#pragma unroll
            for (int j = 0; j < 4; j++) {
                const int n = n0 + wn * 64 + j * 16 + fr;
                const float bb = bias[n];
#pragma unroll
                for (int i = 0; i < 8; i++) {
#pragma unroll
                    for (int r = 0; r < 4; r++) {
                        const float v = fmaxf(acc[i][j][r] + bb, 0.0f);
                        smem[(i * 16 + fq * 4 + r) * 260 + wn * 64 + j * 16 + fr] =
                            __half_as_ushort(__float2half(v));
                    }
                }
            }
        }
        __syncthreads();
#pragma unroll
        for (int it = 0; it < 16; it++) {
            const int row = it * 8 + wv;
            const uint2 d = *(const uint2*)(smem + row * 260 + lane * 4);
            __half* hb = headsb + ((long long)(m0 + pss * 128 + row) * HEADS + h) * 1024
                       + n0 + lane * 4;
            *(uint2*)hb = d;
        }
    }

    // ---- score reduction --------------------------------------------------
#pragma unroll
    for (int off = 1; off < 16; off <<= 1)
#pragma unroll
        for (int i = 0; i < 8; i++)
#pragma unroll
            for (int r = 0; r < 4; r++)
                part[i][r] += __shfl_xor(part[i][r], off, 64);

    if (fr == 0) {
#pragma unroll
        for (int i = 0; i < 8; i++)
#pragma unroll
            for (int r = 0; r < 4; r++)
                scred[wn][wm * 128 + i * 16 + fq * 4 + r] = part[i][r];
    }
    __syncthreads();
    if (tid < 256) {
        const float sv = scred[0][tid] + scred[1][tid] + scred[2][tid] + scred[3][tid];
        scoresp[(long long)(h * 4 + blockIdx.x) * BC + m0 + tid] = sv;
    }
}

// ===========================================================================
// GEMM (convert path, enc/dec): A fp32 (2-region concat), split in-kernel
// via LDS; B async from planes.  Output: hi/lo planes.
// ===========================================================================
template <int RELU>
__global__ __launch_bounds__(256) void gemm_cvt(
    const float* __restrict__ src1, int lda1, int kofs1,
    const float* __restrict__ src2, int lda2, int ksplit,
    const u16* __restrict__ Bhp, const u16* __restrict__ Blp,
    const float* __restrict__ bias,
    u16* __restrict__ Chp, u16* __restrict__ Clp, int MC,
    int K)
{
    __shared__ alignas(16) u16 Ah[4096], Al[4096], Bh[4096], Bl[4096];
    const int tid  = threadIdx.x;
    const int lane = tid & 63;
    const int wv   = tid >> 6;
    const int wm   = wv >> 1, wn = wv & 1;
    const int fr   = lane & 15;
    const int fq   = lane >> 4;
    const int m0   = blockIdx.y * 128;
    const int n0   = blockIdx.x * 128;
    const int fqx  = (fq ^ (fr & 3)) * 8;
    const int lro  = (lane >> 2) * 32 + (((lane & 3) ^ ((lane >> 2) & 3)) * 8);
    const int br0  = wv * 16;
    const int br1  = 64 + wv * 16;
    const int ar   = tid >> 3;           // 0..31
    const int akq  = tid & 7;            // float4 group 0..7
    const int awoff = (((akq >> 1) ^ (ar & 3)) * 8) + (akq & 1) * 4;

    f32x4 acc[4][4];
#pragma unroll
    for (int i = 0; i < 4; i++)
#pragma unroll
        for (int j = 0; j < 4; j++) acc[i][j] = 0;

    const int KT = K >> 5;
    for (int kt = 0; kt < KT; kt++) {
        const int k0 = kt * 32;
        const float* srcp; int ldk, kc;
        if (k0 < ksplit) { srcp = src1; ldk = lda1; kc = k0 + kofs1; }
        else             { srcp = src2; ldk = lda2; kc = k0 - ksplit; }

        const u16* Bg  = Bhp + ((long long)kt * 1024 + n0) * 32;
        const u16* Bg2 = Blp + ((long long)kt * 1024 + n0) * 32;
        gld16(Bg  + br0 * 32 + lro, &Bh[br0 * 32]);
        gld16(Bg  + br1 * 32 + lro, &Bh[br1 * 32]);
        gld16(Bg2 + br0 * 32 + lro, &Bl[br0 * 32]);
        gld16(Bg2 + br1 * 32 + lro, &Bl[br1 * 32]);

#pragma unroll
        for (int it = 0; it < 4; it++) {
            const int row = ar + it * 32;
            const float4 v = *(const float4*)(srcp + (long long)(m0 + row) * ldk + kc + akq * 4);
            uint2 hi, lo;
            splitA4(v, hi, lo);
            *(uint2*)&Ah[row * 32 + awoff] = hi;
            *(uint2*)&Al[row * 32 + awoff] = lo;
        }
        __syncthreads();

        bf16x8 ah[4], al[4], bh[4], bl[4];
#pragma unroll
        for (int i = 0; i < 4; i++) {
            const int off = (wm * 64 + i * 16 + fr) * 32 + fqx;
            ah[i] = *(const bf16x8*)&Ah[off];
            al[i] = *(const bf16x8*)&Al[off];
        }
#pragma unroll
        for (int j = 0; j < 4; j++) {
            const int off = (wn * 64 + j * 16 + fr) * 32 + fqx;
            bh[j] = *(const bf16x8*)&Bh[off];
            bl[j] = *(const bf16x8*)&Bl[off];
        }
#pragma unroll
        for (int i = 0; i < 4; i++)
#pragma unroll
            for (int j = 0; j < 4; j++) {
                acc[i][j] = __builtin_amdgcn_mfma_f32_16x16x32_bf16(ah[i], bh[j], acc[i][j], 0, 0, 0);
                acc[i][j] = __builtin_amdgcn_mfma_f32_16x16x32_bf16(ah[i], bl[j], acc[i][j], 0, 0, 0);
                acc[i][j] = __builtin_amdgcn_mfma_f32_16x16x32_bf16(al[i], bh[j], acc[i][j], 0, 0, 0);
            }
        __syncthreads();
    }

#pragma unroll
    for (int j = 0; j < 4; j++) {
        const int n = n0 + wn * 64 + j * 16 + fr;
        const float bb = bias[n];
#pragma unroll
        for (int i = 0; i < 4; i++) {
#pragma unroll
            for (int r = 0; r < 4; r++) {
                const int m = m0 + wm * 64 + i * 16 + fq * 4 + r;
                float v = acc[i][j][r] + bb;
                if (RELU) v = fmaxf(v, 0.0f);
                u16 h, l;
                split1(v, h, l);
                const long long d = ((long long)(n >> 5) * MC + m) * 32 + (n & 31);
                Chp[d] = h;
                Clp[d] = l;
            }
        }
    }
}

// ---------------------------------------------------------------------------
// context (+fused softmax): per row b, softmax over heads from scoresp
// ([32][BC]: 4 n-tiles per head), then ctx[b][d] = sum_h attn[h]*heads;
// writes hi/lo planes.
// ---------------------------------------------------------------------------
__global__ __launch_bounds__(256) void context_kernel(
    const __half* __restrict__ headsb, const float* __restrict__ scoresp,
    u16* __restrict__ ctx_hi, u16* __restrict__ ctx_lo, int MC, int row0)
{
    __shared__ float sc_s[32];
    __shared__ float attn_s[HEADS];
    const int b = blockIdx.x;
    const int tid = threadIdx.x;
    if (tid < 32) sc_s[tid] = scoresp[(long long)tid * BC + b];
    __syncthreads();
    if (tid == 0) {
        float sc[HEADS];
#pragma unroll
        for (int h = 0; h < HEADS; h++) {
            float s = 0.0f;
#pragma unroll
            for (int nt = 0; nt < 4; nt++) s += sc_s[h * 4 + nt];
            sc[h] = s;
        }
        float mx = sc[0];
#pragma unroll
        for (int h = 1; h < HEADS; h++) mx = fmaxf(mx, sc[h]);
        float e[HEADS], sum = 0.0f;
#pragma unroll
        for (int h = 0; h < HEADS; h++) { e[h] = __expf(sc[h] - mx); sum += e[h]; }
        const float inv = 1.0f / sum;
#pragma unroll
        for (int h = 0; h < HEADS; h++) attn_s[h] = e[h] * inv;
    }
    __syncthreads();

    const int d = tid * 4;
    float w[HEADS];
#pragma unroll
    for (int h = 0; h < HEADS; h++) w[h] = attn_s[h];
    float4 acc = make_float4(0.f, 0.f, 0.f, 0.f);
#pragma unroll
    for (int h = 0; h < HEADS; h++) {
        const __half2* hp = (const __half2*)(headsb + ((long long)b * HEADS + h) * 1024 + d);
        const float2 f0 = __half22float2(hp[0]);
        const float2 f1 = __half22float2(hp[1]);
        acc.x = fmaf(w[h], f0.x, acc.x);
        acc.y = fmaf(w[h], f0.y, acc.y);
        acc.z = fmaf(w[h], f1.x, acc.z);
        acc.w = fmaf(w[h], f1.y, acc.w);
    }
    uint2 hi, lo;
    splitA4(acc, hi, lo);
    const long long off = ((long long)(d >> 5) * MC + row0 + b) * 32 + (d & 31);
    *(uint2*)(ctx_hi + off) = hi;
    *(uint2*)(ctx_lo + off) = lo;
}

// ---------------------------------------------------------------------------
extern "C" void kernel_launch(void* const* d_in, const int* in_sizes, int n_in,
                              void* d_out, int out_size, void* d_ws, size_t ws_size,
                              hipStream_t stream)
{
    const float* s        = (const float*)d_in[0];
    const float* a        = (const float*)d_in[1];
    const float* W_enc_in = (const float*)d_in[2];
    const float* b_enc_in = (const float*)d_in[3];
    const float* W_dec_in = (const float*)d_in[4];
    const float* b_dec_in = (const float*)d_in[5];
    const float* W_eh     = (const float*)d_in[6];
    const float* b_eh     = (const float*)d_in[7];
    const float* W_heads  = (const float*)d_in[8];
    const float* b_heads  = (const float*)d_in[9];
    const float* W_dh     = (const float*)d_in[10];
    const float* b_dh     = (const float*)d_in[11];
    const float* W1       = (const float*)d_in[12];
    const float* b1       = (const float*)d_in[13];
    const float* W2       = (const float*)d_in[14];
    const float* b2       = (const float*)d_in[15];
    float* q_out = (float*)d_out;

    // ---- weight plane layout (shorts) -------------------------------------
    u16* P = (u16*)d_ws;
    u16* enc_hi = P; P += 557056;      // 544*1024
    u16* enc_lo = P; P += 557056;
    u16* dec_hi = P; P += 98304;       // 96*1024
    u16* dec_lo = P; P += 98304;
    u16* eh_hi  = P; P += 1048576;
    u16* eh_lo  = P; P += 1048576;
    u16* dh_hi  = P; P += 1048576;
    u16* dh_lo  = P; P += 1048576;
    u16* w1_hi  = P; P += 1048576;
    u16* w1_lo  = P; P += 1048576;
    u16* wh_hi  = P; P += 8388608;     // 8*1024*1024
    u16* wh_lo  = P; P += 8388608;
    char* act = (char*)P;              // 48,758,784 bytes consumed

    const dim3 blk(256);
    const dim3 blk512(512);

    // zero q (fused-fc2 atomics accumulate onto it; graph-replay safe)
    hipMemsetAsync(q_out, 0, BATCH * sizeof(float), stream);

    // ---- weight conversions: ONE launch -----------------------------------
    WSplitArgs wa;
    wa.src[0] = W_eh;    wa.hi[0] = eh_hi;  wa.lo[0] = eh_lo;
    wa.src[1] = W_dh;    wa.hi[1] = dh_hi;  wa.lo[1] = dh_lo;
    wa.src[2] = W1;      wa.hi[2] = w1_hi;  wa.lo[2] = w1_lo;
    wa.src[3] = W_heads; wa.hi[3] = wh_hi;  wa.lo[3] = wh_lo;
    wa.src[4] = W_enc_in; wa.hi[4] = enc_hi; wa.lo[4] = enc_lo;
    wa.src[5] = W_dec_in; wa.hi[5] = dec_hi; wa.lo[5] = dec_lo;
    split_weight_all<<<dim3(32, 8, 13), blk, 0, stream>>>(wa);

    const bool high = (ws_size >= 150011904ULL);

    if (high) {
        u16*    bufA_hi = (u16*)act;
        u16*    bufA_lo = bufA_hi + 8388608;
        __half* headsb  = (__half*)act;
        u16*    encH_hi = (u16*)(act + 33554432);
        u16*    encH_lo = encH_hi + 8388608;
        float*  decH    = (float*)(act + 2LL * 33554432);
        float*  scoresp = (float*)(act + 3LL * 33554432);

        const dim3 ggc(8, 64, 1);      // cvt kernels: 128-row tiles
        const dim3 ggf(8, 32, 1);      // gemm_fast: 256x128 tiles
        gemm_cvt<0><<<ggc, blk, 0, stream>>>(s, 512, 0, a, 128, 512,
            enc_hi, enc_lo, b_enc_in, bufA_hi, bufA_lo, 8192, 544);
        gemm_fast<1, 1><<<ggf, blk512, 0, stream>>>(bufA_hi, bufA_lo, 8192, 0,
            eh_hi, eh_lo, b_eh, nullptr, encH_hi, encH_lo, 8192, 1024,
            nullptr, nullptr, nullptr);
        gemm_cvt<0><<<ggc, blk, 0, stream>>>(a, 128, 32, a, 128, 1 << 28,
            dec_hi, dec_lo, b_dec_in, bufA_hi, bufA_lo, 8192, 96);
        gemm_fast<1, 0><<<ggf, blk512, 0, stream>>>(bufA_hi, bufA_lo, 8192, 0,
            dh_hi, dh_lo, b_dh, decH, nullptr, nullptr, 0, 1024,
            nullptr, nullptr, nullptr);

        for (int c = 0; c < BATCH / BC; c++) {
            heads_kernel<<<dim3(4, BC / 256, 8), blk512, 0, stream>>>(
                encH_hi, encH_lo, 8192, c * BC, wh_hi, wh_lo, b_heads,
                decH + (long long)c * BC * 1024, headsb, scoresp);
            context_kernel<<<dim3(BC), blk, 0, stream>>>(
                headsb, scoresp, encH_hi, encH_lo, 8192, c * BC);
        }
        // w1 GEMM with fused fc2 (atomicAdd into q_out)
        gemm_fast<1, 2><<<ggf, blk512, 0, stream>>>(encH_hi, encH_lo, 8192, 0,
            w1_hi, w1_lo, b1, nullptr, nullptr, nullptr, 0, 1024,
            W2, b2, q_out);
    } else {
        __half* headsb  = (__half*)act;
        u16*    bufA_hi = (u16*)act;
        u16*    bufA_lo = bufA_hi + 2097152;
        u16*    encH_hi = (u16*)(act + 33554432);
        u16*    encH_lo = encH_hi + 2097152;
        float*  decH    = (float*)(act + 33554432 + 8388608);
        float*  scoresp = (float*)(act + 33554432 + 2LL * 8388608);

        const dim3 ggc(8, BC / 128, 1);
        const dim3 ggf(8, BC / 256, 1);
        for (int c = 0; c < BATCH / BC; c++) {
            const float* sC = s + (long long)c * BC * 512;
            const float* aC = a + (long long)c * BC * 128;
            gemm_cvt<0><<<ggc, blk, 0, stream>>>(sC, 512, 0, aC, 128, 512,
                enc_hi, enc_lo, b_enc_in, bufA_hi, bufA_lo, BC, 544);
            gemm_fast<1, 1><<<ggf, blk512, 0, stream>>>(bufA_hi, bufA_lo, BC, 0,
                eh_hi, eh_lo, b_eh, nullptr, encH_hi, encH_lo, BC, 1024,
                nullptr, nullptr, nullptr);
            gemm_cvt<0><<<ggc, blk, 0, stream>>>(aC, 128, 32, aC, 128, 1 << 28,
                dec_hi, dec_lo, b_dec_in, bufA_hi, bufA_lo, BC, 96);
            gemm_fast<1, 0><<<ggf, blk512, 0, stream>>>(bufA_hi, bufA_lo, BC, 0,
                dh_hi, dh_lo, b_dh, decH, nullptr, nullptr, 0, 1024,
                nullptr, nullptr, nullptr);
            heads_kernel<<<dim3(4, BC / 256, 8), blk512, 0, stream>>>(
                encH_hi, encH_lo, BC, 0, wh_hi, wh_lo, b_heads,
                decH, headsb, scoresp);
            context_kernel<<<dim3(BC), blk, 0, stream>>>(
                headsb, scoresp, encH_hi, encH_lo, BC, 0);
            gemm_fast<1, 2><<<ggf, blk512, 0, stream>>>(encH_hi, encH_lo, BC, 0,
                w1_hi, w1_lo, b1, nullptr, nullptr, nullptr, 0, 1024,
                W2, b2, q_out + (long long)c * BC);
        }
    }
}